// Round 1
// baseline (1497.937 us; speedup 1.0000x reference)
//
#include <hip/hip_runtime.h>

#define NN 100000
#define NE 1600000
#define FD 128
#define NC 40

// ---- workspace layout (bytes, 128-aligned blocks) ----
// total ~110.4 MB
#define WS_DEG      0u            // N int
#define WS_OFF      400128u       // N+1 int
#define WS_CUR      800512u       // N int
#define WS_INVDEG   1200640u      // N float
#define WS_PART     1600768u      // 256 int
#define WS_CSR      1601792u      // E int
#define WS_MEAN     8001792u      // N*128 float
#define WS_H        59201792u     // N*128 float

// ---------------- CSR build ----------------
__global__ void k_count(const int* __restrict__ dst, int* __restrict__ deg) {
    int i = blockIdx.x * blockDim.x + threadIdx.x;
    int stride = gridDim.x * blockDim.x;
    for (int e = i; e < NE; e += stride)
        atomicAdd(&deg[dst[e]], 1);
}

__global__ void k_scan1(const int* __restrict__ deg, int* __restrict__ off,
                        int* __restrict__ part) {
    __shared__ int s[256];
    int t = threadIdx.x;
    int base = blockIdx.x * 1024 + t * 4;
    int v[4]; int tsum = 0;
#pragma unroll
    for (int j = 0; j < 4; ++j) {
        int idx = base + j;
        v[j] = (idx < NN) ? deg[idx] : 0;
        tsum += v[j];
    }
    s[t] = tsum;
    __syncthreads();
    for (int d = 1; d < 256; d <<= 1) {
        int x = (t >= d) ? s[t - d] : 0;
        __syncthreads();
        s[t] += x;
        __syncthreads();
    }
    int excl = s[t] - tsum;
    if (t == 255) part[blockIdx.x] = s[t];
    int p = excl;
#pragma unroll
    for (int j = 0; j < 4; ++j) {
        int idx = base + j;
        if (idx < NN) off[idx] = p;
        p += v[j];
    }
}

__global__ void k_scan2(int* __restrict__ part, int n) {
    __shared__ int s[256];
    int t = threadIdx.x;
    int v = (t < n) ? part[t] : 0;
    s[t] = v;
    __syncthreads();
    for (int d = 1; d < 256; d <<= 1) {
        int x = (t >= d) ? s[t - d] : 0;
        __syncthreads();
        s[t] += x;
        __syncthreads();
    }
    if (t < n) part[t] = s[t] - v;   // exclusive
}

__global__ void k_scan3(int* __restrict__ off, const int* __restrict__ part,
                        int* __restrict__ cur, const int* __restrict__ deg,
                        float* __restrict__ invdeg) {
    int i = blockIdx.x * blockDim.x + threadIdx.x;
    if (i == 0) off[NN] = NE;
    if (i < NN) {
        int o = off[i] + part[i >> 10];
        off[i] = o;
        cur[i] = o;
        int d = deg[i];
        invdeg[i] = 1.0f / (float)(d > 0 ? d : 1);
    }
}

__global__ void k_scatter(const int* __restrict__ ei, int* __restrict__ cur,
                          int* __restrict__ csr) {
    int i = blockIdx.x * blockDim.x + threadIdx.x;
    int stride = gridDim.x * blockDim.x;
    for (int e = i; e < NE; e += stride) {
        int s = ei[e];
        int d = ei[NE + e];
        int pos = atomicAdd(&cur[d], 1);
        csr[pos] = s;
    }
}

// ---------------- mean aggregation: one wave per node ----------------
__global__ __launch_bounds__(256) void k_agg(const float* __restrict__ X,
                                             const int* __restrict__ off,
                                             const int* __restrict__ csr,
                                             const float* __restrict__ invdeg,
                                             float* __restrict__ M) {
    int wid = (blockIdx.x * 256 + threadIdx.x) >> 6;
    int lane = threadIdx.x & 63;
    if (wid >= NN) return;
    int s0 = off[wid], s1 = off[wid + 1];
    float ax = 0.f, ay = 0.f;
    for (int e = s0; e < s1; ++e) {
        int r = csr[e];
        float2 v = *reinterpret_cast<const float2*>(X + (size_t)r * FD + lane * 2);
        ax += v.x; ay += v.y;
    }
    float w = invdeg[wid];
    float2 o; o.x = ax * w; o.y = ay * w;
    *reinterpret_cast<float2*>(M + (size_t)wid * FD + lane * 2) = o;
}

// ---------------- fused dual GEMM (+ optional classifier) ----------------
// out128 = relu(M @ Wl^T + X @ Wr^T + bias)          (FUSE=false: write [N,128])
// FUSE=true: additionally out = h2 @ Wc^T + bc       (write [N,40])
template <bool FUSE>
__global__ __launch_bounds__(256) void k_gemm(const float* __restrict__ M,
                                              const float* __restrict__ X,
                                              const float* __restrict__ Wl,
                                              const float* __restrict__ Wr,
                                              const float* __restrict__ bias,
                                              const float* __restrict__ Wc,
                                              const float* __restrict__ bc,
                                              float* __restrict__ out) {
    __shared__ __align__(16) float smem[FUSE ? 13728 : 6400];
    float* As = smem;          // [32][68]  k-major A chunk
    float* Ws = smem + 2176;   // [32][132] k-major W chunk
    const int tid = threadIdx.x;
    const int tx = tid & 15;   // out group: o = tx*8 + j
    const int ty = tid >> 4;   // node group: n = ty*4 + i
    const int nb = blockIdx.x * 64;

    float acc[4][8];
#pragma unroll
    for (int i = 0; i < 4; ++i)
#pragma unroll
        for (int j = 0; j < 8; ++j) acc[i][j] = 0.f;

    for (int s = 0; s < 2; ++s) {
        const float* A = s ? X : M;
        const float* W = s ? Wr : Wl;
        for (int kc = 0; kc < FD; kc += 32) {
            __syncthreads();
            // stage A chunk transposed: As[k][n]
#pragma unroll
            for (int r = 0; r < 2; ++r) {
                int slot = tid + 256 * r;     // < 512
                int n = slot >> 3, c = slot & 7;
                int gn = nb + n;
                float4 v = make_float4(0.f, 0.f, 0.f, 0.f);
                if (gn < NN)
                    v = *reinterpret_cast<const float4*>(A + (size_t)gn * FD + kc + c * 4);
                As[(c * 4 + 0) * 68 + n] = v.x;
                As[(c * 4 + 1) * 68 + n] = v.y;
                As[(c * 4 + 2) * 68 + n] = v.z;
                As[(c * 4 + 3) * 68 + n] = v.w;
            }
            // stage W chunk transposed: Ws[k][o]
#pragma unroll
            for (int r = 0; r < 4; ++r) {
                int slot = tid + 256 * r;     // < 1024
                int o = slot >> 3, c = slot & 7;
                float4 v = *reinterpret_cast<const float4*>(W + o * FD + kc + c * 4);
                Ws[(c * 4 + 0) * 132 + o] = v.x;
                Ws[(c * 4 + 1) * 132 + o] = v.y;
                Ws[(c * 4 + 2) * 132 + o] = v.z;
                Ws[(c * 4 + 3) * 132 + o] = v.w;
            }
            __syncthreads();
#pragma unroll
            for (int k = 0; k < 32; ++k) {
                float4 a  = *reinterpret_cast<const float4*>(&As[k * 68 + ty * 4]);
                float4 w0 = *reinterpret_cast<const float4*>(&Ws[k * 132 + tx * 8]);
                float4 w1 = *reinterpret_cast<const float4*>(&Ws[k * 132 + tx * 8 + 4]);
                float av[4] = {a.x, a.y, a.z, a.w};
                float wv[8] = {w0.x, w0.y, w0.z, w0.w, w1.x, w1.y, w1.z, w1.w};
#pragma unroll
                for (int i = 0; i < 4; ++i)
#pragma unroll
                    for (int j = 0; j < 8; ++j) acc[i][j] += av[i] * wv[j];
            }
        }
    }

    float bz[8];
#pragma unroll
    for (int j = 0; j < 8; ++j) bz[j] = bias[tx * 8 + j];

    if (!FUSE) {
#pragma unroll
        for (int i = 0; i < 4; ++i) {
            int gn = nb + ty * 4 + i;
            if (gn < NN) {
                float4 o0, o1;
                o0.x = fmaxf(acc[i][0] + bz[0], 0.f);
                o0.y = fmaxf(acc[i][1] + bz[1], 0.f);
                o0.z = fmaxf(acc[i][2] + bz[2], 0.f);
                o0.w = fmaxf(acc[i][3] + bz[3], 0.f);
                o1.x = fmaxf(acc[i][4] + bz[4], 0.f);
                o1.y = fmaxf(acc[i][5] + bz[5], 0.f);
                o1.z = fmaxf(acc[i][6] + bz[6], 0.f);
                o1.w = fmaxf(acc[i][7] + bz[7], 0.f);
                *reinterpret_cast<float4*>(out + (size_t)gn * FD + tx * 8) = o0;
                *reinterpret_cast<float4*>(out + (size_t)gn * FD + tx * 8 + 4) = o1;
            }
        }
    } else {
        float* Hs  = smem;           // [64][132]
        float* Wcs = smem + 8448;    // [40][132]
        __syncthreads();             // done reading As/Ws
#pragma unroll
        for (int i = 0; i < 4; ++i) {
            int n = ty * 4 + i;
            float4 o0, o1;
            o0.x = fmaxf(acc[i][0] + bz[0], 0.f);
            o0.y = fmaxf(acc[i][1] + bz[1], 0.f);
            o0.z = fmaxf(acc[i][2] + bz[2], 0.f);
            o0.w = fmaxf(acc[i][3] + bz[3], 0.f);
            o1.x = fmaxf(acc[i][4] + bz[4], 0.f);
            o1.y = fmaxf(acc[i][5] + bz[5], 0.f);
            o1.z = fmaxf(acc[i][6] + bz[6], 0.f);
            o1.w = fmaxf(acc[i][7] + bz[7], 0.f);
            *reinterpret_cast<float4*>(&Hs[n * 132 + tx * 8]) = o0;
            *reinterpret_cast<float4*>(&Hs[n * 132 + tx * 8 + 4]) = o1;
        }
        // stage Wc (row-major copy): Wcs[cls][k]
#pragma unroll
        for (int r = 0; r < 5; ++r) {
            int slot = tid + 256 * r;      // < 1280
            int cls = slot >> 5;
            int c4 = slot & 31;
            float4 v = *reinterpret_cast<const float4*>(Wc + cls * FD + c4 * 4);
            *reinterpret_cast<float4*>(&Wcs[cls * 132 + c4 * 4]) = v;
        }
        __syncthreads();
        const int tx2 = tid & 7;     // cls = tx2*5 + j
        const int ty2 = tid >> 3;    // node = ty2*2 + i
        float acc2[2][5];
#pragma unroll
        for (int i = 0; i < 2; ++i)
#pragma unroll
            for (int j = 0; j < 5; ++j) acc2[i][j] = 0.f;
#pragma unroll
        for (int k = 0; k < FD; k += 4) {
            float4 h0 = *reinterpret_cast<const float4*>(&Hs[(ty2 * 2 + 0) * 132 + k]);
            float4 h1 = *reinterpret_cast<const float4*>(&Hs[(ty2 * 2 + 1) * 132 + k]);
#pragma unroll
            for (int j = 0; j < 5; ++j) {
                float4 w = *reinterpret_cast<const float4*>(&Wcs[(tx2 * 5 + j) * 132 + k]);
                acc2[0][j] += h0.x * w.x + h0.y * w.y + h0.z * w.z + h0.w * w.w;
                acc2[1][j] += h1.x * w.x + h1.y * w.y + h1.z * w.z + h1.w * w.w;
            }
        }
#pragma unroll
        for (int i = 0; i < 2; ++i) {
            int gn = nb + ty2 * 2 + i;
            if (gn < NN) {
#pragma unroll
                for (int j = 0; j < 5; ++j)
                    out[(size_t)gn * NC + tx2 * 5 + j] = acc2[i][j] + bc[tx2 * 5 + j];
            }
        }
    }
}

extern "C" void kernel_launch(void* const* d_in, const int* in_sizes, int n_in,
                              void* d_out, int out_size, void* d_ws, size_t ws_size,
                              hipStream_t stream) {
    const float* x   = (const float*)d_in[0];
    const int*   ei  = (const int*)d_in[1];   // [2, E] int32 (src row then dst row)
    const float* W1l = (const float*)d_in[3];
    const float* b1l = (const float*)d_in[4];
    const float* W1r = (const float*)d_in[5];
    const float* W2l = (const float*)d_in[6];
    const float* b2l = (const float*)d_in[7];
    const float* W2r = (const float*)d_in[8];
    const float* Wc  = (const float*)d_in[9];
    const float* bc  = (const float*)d_in[10];
    float* out = (float*)d_out;

    char* ws = (char*)d_ws;
    int*   deg    = (int*)(ws + WS_DEG);
    int*   off    = (int*)(ws + WS_OFF);
    int*   cur    = (int*)(ws + WS_CUR);
    float* invdeg = (float*)(ws + WS_INVDEG);
    int*   part   = (int*)(ws + WS_PART);
    int*   csr    = (int*)(ws + WS_CSR);
    float* mean   = (float*)(ws + WS_MEAN);
    float* h      = (float*)(ws + WS_H);

    hipMemsetAsync(deg, 0, NN * sizeof(int), stream);
    k_count<<<2048, 256, 0, stream>>>(ei + NE, deg);
    int G1 = (NN + 1023) / 1024;  // 98
    k_scan1<<<G1, 256, 0, stream>>>(deg, off, part);
    k_scan2<<<1, 256, 0, stream>>>(part, G1);
    k_scan3<<<(NN + 255) / 256, 256, 0, stream>>>(off, part, cur, deg, invdeg);
    k_scatter<<<2048, 256, 0, stream>>>(ei, cur, csr);

    // layer 1
    k_agg<<<(NN + 3) / 4, 256, 0, stream>>>(x, off, csr, invdeg, mean);
    k_gemm<false><<<(NN + 63) / 64, 256, 0, stream>>>(mean, x, W1l, W1r, b1l,
                                                      nullptr, nullptr, h);
    // layer 2 + fused classifier
    k_agg<<<(NN + 3) / 4, 256, 0, stream>>>(h, off, csr, invdeg, mean);
    k_gemm<true><<<(NN + 63) / 64, 256, 0, stream>>>(mean, h, W2l, W2r, b2l,
                                                     Wc, bc, out);
}

// Round 2
// 679.977 us; speedup vs baseline: 2.2029x; 2.2029x over previous
//
#include <hip/hip_runtime.h>

#define NN 100000
#define NE 1600000
#define FD 128
#define NC 40

// ---- workspace layout (bytes) ----
#define WS_DEG      0u            // N int
#define WS_OFF      400128u       // N+1 int
#define WS_CUR      800512u       // N int
#define WS_INVDEG   1200640u      // N float
#define WS_PART     1600768u      // 256 int
#define WS_CSR      1601792u      // E int
#define WS_MEAN     8001792u      // N*128 float (also holds h2 / classifier input)
#define WS_H        59201792u     // N*128 float

// ---------------- CSR build ----------------
__global__ void k_count(const int* __restrict__ dst, int* __restrict__ deg) {
    int i = blockIdx.x * blockDim.x + threadIdx.x;
    int stride = gridDim.x * blockDim.x;
    for (int e = i; e < NE; e += stride)
        atomicAdd(&deg[dst[e]], 1);
}

__global__ void k_scan1(const int* __restrict__ deg, int* __restrict__ off,
                        int* __restrict__ part) {
    __shared__ int s[256];
    int t = threadIdx.x;
    int base = blockIdx.x * 1024 + t * 4;
    int v[4]; int tsum = 0;
#pragma unroll
    for (int j = 0; j < 4; ++j) {
        int idx = base + j;
        v[j] = (idx < NN) ? deg[idx] : 0;
        tsum += v[j];
    }
    s[t] = tsum;
    __syncthreads();
    for (int d = 1; d < 256; d <<= 1) {
        int x = (t >= d) ? s[t - d] : 0;
        __syncthreads();
        s[t] += x;
        __syncthreads();
    }
    int excl = s[t] - tsum;
    if (t == 255) part[blockIdx.x] = s[t];
    int p = excl;
#pragma unroll
    for (int j = 0; j < 4; ++j) {
        int idx = base + j;
        if (idx < NN) off[idx] = p;
        p += v[j];
    }
}

__global__ void k_scan2(int* __restrict__ part, int n) {
    __shared__ int s[256];
    int t = threadIdx.x;
    int v = (t < n) ? part[t] : 0;
    s[t] = v;
    __syncthreads();
    for (int d = 1; d < 256; d <<= 1) {
        int x = (t >= d) ? s[t - d] : 0;
        __syncthreads();
        s[t] += x;
        __syncthreads();
    }
    if (t < n) part[t] = s[t] - v;   // exclusive
}

__global__ void k_scan3(int* __restrict__ off, const int* __restrict__ part,
                        int* __restrict__ cur, const int* __restrict__ deg,
                        float* __restrict__ invdeg) {
    int i = blockIdx.x * blockDim.x + threadIdx.x;
    if (i == 0) off[NN] = NE;
    if (i < NN) {
        int o = off[i] + part[i >> 10];
        off[i] = o;
        cur[i] = o;
        int d = deg[i];
        invdeg[i] = 1.0f / (float)(d > 0 ? d : 1);
    }
}

__global__ void k_scatter(const int* __restrict__ ei, int* __restrict__ cur,
                          int* __restrict__ csr) {
    int i = blockIdx.x * blockDim.x + threadIdx.x;
    int stride = gridDim.x * blockDim.x;
    for (int e = i; e < NE; e += stride) {
        int s = ei[e];
        int d = ei[NE + e];
        int pos = atomicAdd(&cur[d], 1);
        csr[pos] = s;
    }
}

// ---------------- mean aggregation: one wave per node ----------------
__global__ __launch_bounds__(256) void k_agg(const float* __restrict__ X,
                                             const int* __restrict__ off,
                                             const int* __restrict__ csr,
                                             const float* __restrict__ invdeg,
                                             float* __restrict__ M) {
    int wid = (blockIdx.x * 256 + threadIdx.x) >> 6;
    int lane = threadIdx.x & 63;
    if (wid >= NN) return;
    int s0 = off[wid], s1 = off[wid + 1];
    float ax = 0.f, ay = 0.f;
    int e = s0;
    for (; e + 1 < s1; e += 2) {
        int r0 = csr[e];
        int r1 = csr[e + 1];
        float2 v0 = *reinterpret_cast<const float2*>(X + (size_t)r0 * FD + lane * 2);
        float2 v1 = *reinterpret_cast<const float2*>(X + (size_t)r1 * FD + lane * 2);
        ax += v0.x + v1.x; ay += v0.y + v1.y;
    }
    if (e < s1) {
        int r = csr[e];
        float2 v = *reinterpret_cast<const float2*>(X + (size_t)r * FD + lane * 2);
        ax += v.x; ay += v.y;
    }
    float w = invdeg[wid];
    float2 o; o.x = ax * w; o.y = ay * w;
    *reinterpret_cast<float2*>(M + (size_t)wid * FD + lane * 2) = o;
}

// ---------------- dual GEMM: out = relu(M@Wl^T + X@Wr^T + b) ----------------
// M/out may alias (layer 2 writes h2 over mean): each block writes only rows
// it has fully consumed, so no __restrict__ on M/out.
__global__ __launch_bounds__(256, 4) void k_gemm(const float* M,
                                                 const float* __restrict__ X,
                                                 const float* __restrict__ Wl,
                                                 const float* __restrict__ Wr,
                                                 const float* __restrict__ bias,
                                                 float* out) {
    __shared__ __align__(16) float As[32 * 68];    // [k][node]
    __shared__ __align__(16) float Ws[32 * 132];   // [k][out]
    const int tid = threadIdx.x;
    const int tx = tid & 15;   // o = tx*8 + j
    const int ty = tid >> 4;   // n = ty*4 + i
    const int nb = blockIdx.x * 64;

    float acc[4][8] = {};

    for (int c = 0; c < 8; ++c) {
        const float* A = (c < 4) ? M : X;
        const float* W = (c < 4) ? Wl : Wr;
        const int kc = (c & 3) * 32;
        __syncthreads();
        // stage A chunk transposed: As[k][n]
#pragma unroll
        for (int r = 0; r < 2; ++r) {
            int slot = tid + 256 * r;     // < 512
            int n = slot >> 3, cc = slot & 7;
            int gn = nb + n;
            float4 v = make_float4(0.f, 0.f, 0.f, 0.f);
            if (gn < NN)
                v = *reinterpret_cast<const float4*>(A + (size_t)gn * FD + kc + cc * 4);
            As[(cc * 4 + 0) * 68 + n] = v.x;
            As[(cc * 4 + 1) * 68 + n] = v.y;
            As[(cc * 4 + 2) * 68 + n] = v.z;
            As[(cc * 4 + 3) * 68 + n] = v.w;
        }
        // stage W chunk transposed: Ws[k][o]
#pragma unroll
        for (int r = 0; r < 4; ++r) {
            int slot = tid + 256 * r;     // < 1024
            int o = slot >> 3, cc = slot & 7;
            float4 v = *reinterpret_cast<const float4*>(W + o * FD + kc + cc * 4);
            Ws[(cc * 4 + 0) * 132 + o] = v.x;
            Ws[(cc * 4 + 1) * 132 + o] = v.y;
            Ws[(cc * 4 + 2) * 132 + o] = v.z;
            Ws[(cc * 4 + 3) * 132 + o] = v.w;
        }
        __syncthreads();
#pragma unroll 8
        for (int k = 0; k < 32; ++k) {
            float4 a  = *reinterpret_cast<const float4*>(&As[k * 68 + ty * 4]);
            float4 w0 = *reinterpret_cast<const float4*>(&Ws[k * 132 + tx * 8]);
            float4 w1 = *reinterpret_cast<const float4*>(&Ws[k * 132 + tx * 8 + 4]);
            float av[4] = {a.x, a.y, a.z, a.w};
            float wv[8] = {w0.x, w0.y, w0.z, w0.w, w1.x, w1.y, w1.z, w1.w};
#pragma unroll
            for (int i = 0; i < 4; ++i)
#pragma unroll
                for (int j = 0; j < 8; ++j) acc[i][j] += av[i] * wv[j];
        }
    }

    float bz[8];
#pragma unroll
    for (int j = 0; j < 8; ++j) bz[j] = bias[tx * 8 + j];

#pragma unroll
    for (int i = 0; i < 4; ++i) {
        int gn = nb + ty * 4 + i;
        if (gn < NN) {
            float4 o0, o1;
            o0.x = fmaxf(acc[i][0] + bz[0], 0.f);
            o0.y = fmaxf(acc[i][1] + bz[1], 0.f);
            o0.z = fmaxf(acc[i][2] + bz[2], 0.f);
            o0.w = fmaxf(acc[i][3] + bz[3], 0.f);
            o1.x = fmaxf(acc[i][4] + bz[4], 0.f);
            o1.y = fmaxf(acc[i][5] + bz[5], 0.f);
            o1.z = fmaxf(acc[i][6] + bz[6], 0.f);
            o1.w = fmaxf(acc[i][7] + bz[7], 0.f);
            *reinterpret_cast<float4*>(out + (size_t)gn * FD + tx * 8) = o0;
            *reinterpret_cast<float4*>(out + (size_t)gn * FD + tx * 8 + 4) = o1;
        }
    }
}

// ---------------- classifier: out = H @ Wc^T + bc ----------------
__global__ __launch_bounds__(256) void k_cls(const float* __restrict__ H,
                                             const float* __restrict__ Wc,
                                             const float* __restrict__ bc,
                                             float* __restrict__ out) {
    __shared__ __align__(16) float Wcs[40 * 132];
    const int tid = threadIdx.x;
#pragma unroll
    for (int r = 0; r < 5; ++r) {
        int slot = tid + 256 * r;      // < 1280
        int cls = slot >> 5;
        int c4 = slot & 31;
        float4 v = *reinterpret_cast<const float4*>(Wc + cls * FD + c4 * 4);
        *reinterpret_cast<float4*>(&Wcs[cls * 132 + c4 * 4]) = v;
    }
    __syncthreads();
    const int tx = tid & 7;      // cls = tx*5 + j
    const int ty = tid >> 3;     // node = nb + ty*2 + i
    const int nb = blockIdx.x * 64;
    const int n0 = nb + ty * 2;
    const int n1 = n0 + 1;
    const bool v0 = n0 < NN, v1 = n1 < NN;
    float acc[2][5] = {};
#pragma unroll 4
    for (int k = 0; k < FD; k += 4) {
        float4 h0 = v0 ? *reinterpret_cast<const float4*>(H + (size_t)n0 * FD + k)
                       : make_float4(0.f, 0.f, 0.f, 0.f);
        float4 h1 = v1 ? *reinterpret_cast<const float4*>(H + (size_t)n1 * FD + k)
                       : make_float4(0.f, 0.f, 0.f, 0.f);
#pragma unroll
        for (int j = 0; j < 5; ++j) {
            float4 w = *reinterpret_cast<const float4*>(&Wcs[(tx * 5 + j) * 132 + k]);
            acc[0][j] += h0.x * w.x + h0.y * w.y + h0.z * w.z + h0.w * w.w;
            acc[1][j] += h1.x * w.x + h1.y * w.y + h1.z * w.z + h1.w * w.w;
        }
    }
    if (v0) {
#pragma unroll
        for (int j = 0; j < 5; ++j)
            out[(size_t)n0 * NC + tx * 5 + j] = acc[0][j] + bc[tx * 5 + j];
    }
    if (v1) {
#pragma unroll
        for (int j = 0; j < 5; ++j)
            out[(size_t)n1 * NC + tx * 5 + j] = acc[1][j] + bc[tx * 5 + j];
    }
}

extern "C" void kernel_launch(void* const* d_in, const int* in_sizes, int n_in,
                              void* d_out, int out_size, void* d_ws, size_t ws_size,
                              hipStream_t stream) {
    const float* x   = (const float*)d_in[0];
    const int*   ei  = (const int*)d_in[1];   // [2, E] int32 (src row then dst row)
    const float* W1l = (const float*)d_in[3];
    const float* b1l = (const float*)d_in[4];
    const float* W1r = (const float*)d_in[5];
    const float* W2l = (const float*)d_in[6];
    const float* b2l = (const float*)d_in[7];
    const float* W2r = (const float*)d_in[8];
    const float* Wc  = (const float*)d_in[9];
    const float* bc  = (const float*)d_in[10];
    float* out = (float*)d_out;

    char* ws = (char*)d_ws;
    int*   deg    = (int*)(ws + WS_DEG);
    int*   off    = (int*)(ws + WS_OFF);
    int*   cur    = (int*)(ws + WS_CUR);
    float* invdeg = (float*)(ws + WS_INVDEG);
    int*   part   = (int*)(ws + WS_PART);
    int*   csr    = (int*)(ws + WS_CSR);
    float* mean   = (float*)(ws + WS_MEAN);
    float* h      = (float*)(ws + WS_H);

    hipMemsetAsync(deg, 0, NN * sizeof(int), stream);
    k_count<<<2048, 256, 0, stream>>>(ei + NE, deg);
    int G1 = (NN + 1023) / 1024;  // 98
    k_scan1<<<G1, 256, 0, stream>>>(deg, off, part);
    k_scan2<<<1, 256, 0, stream>>>(part, G1);
    k_scan3<<<(NN + 255) / 256, 256, 0, stream>>>(off, part, cur, deg, invdeg);
    k_scatter<<<2048, 256, 0, stream>>>(ei, cur, csr);

    const int GG = (NN + 63) / 64;   // 1563

    // layer 1
    k_agg<<<(NN + 3) / 4, 256, 0, stream>>>(x, off, csr, invdeg, mean);
    k_gemm<<<GG, 256, 0, stream>>>(mean, x, W1l, W1r, b1l, h);
    // layer 2 (h2 overwrites mean: safe, block-local rows only)
    k_agg<<<(NN + 3) / 4, 256, 0, stream>>>(h, off, csr, invdeg, mean);
    k_gemm<<<GG, 256, 0, stream>>>(mean, h, W2l, W2r, b2l, mean);
    // classifier
    k_cls<<<GG, 256, 0, stream>>>(mean, Wc, bc, out);
}

// Round 3
// 462.510 us; speedup vs baseline: 3.2387x; 1.4702x over previous
//
#include <hip/hip_runtime.h>

#define NN 100000
#define NE 1600000
#define FD 128
#define NC 40

typedef __attribute__((ext_vector_type(8))) short short8;
typedef __attribute__((ext_vector_type(4))) float f32x4;

// ---- workspace layout (bytes) ----
#define WS_DEG      0u
#define WS_OFF      401408u
#define WS_INVDEG   802816u
#define WS_PART     1204224u
#define WS_CSR      1205248u      // E int (6.4 MB)
#define WS_MEAN     7605248u      // N*128 f32 (51.2 MB); also holds h2
#define WS_H        58805248u     // N*128 f32; doubles as packed u64[NE] during CSR build

// ---------------- CSR build ----------------
// pass 1: rank ticket (one atomic pass) + coalesced packed write
__global__ void k_ticket(const int* __restrict__ ei, int* __restrict__ deg,
                         unsigned long long* __restrict__ packed) {
    int i = blockIdx.x * blockDim.x + threadIdx.x;
    int stride = gridDim.x * blockDim.x;
    for (int e = i; e < NE; e += stride) {
        int s = ei[e];
        int d = ei[NE + e];
        unsigned r = atomicAdd(&deg[d], 1);
        packed[e] = (unsigned long long)(unsigned)s |
                    ((unsigned long long)(unsigned)d << 17) |
                    ((unsigned long long)r << 34);
    }
}

__global__ void k_scan1(const int* __restrict__ deg, int* __restrict__ off,
                        int* __restrict__ part) {
    __shared__ int s[256];
    int t = threadIdx.x;
    int base = blockIdx.x * 1024 + t * 4;
    int v[4]; int tsum = 0;
#pragma unroll
    for (int j = 0; j < 4; ++j) {
        int idx = base + j;
        v[j] = (idx < NN) ? deg[idx] : 0;
        tsum += v[j];
    }
    s[t] = tsum;
    __syncthreads();
    for (int d = 1; d < 256; d <<= 1) {
        int x = (t >= d) ? s[t - d] : 0;
        __syncthreads();
        s[t] += x;
        __syncthreads();
    }
    int excl = s[t] - tsum;
    if (t == 255) part[blockIdx.x] = s[t];
    int p = excl;
#pragma unroll
    for (int j = 0; j < 4; ++j) {
        int idx = base + j;
        if (idx < NN) off[idx] = p;
        p += v[j];
    }
}

__global__ void k_scan2(int* __restrict__ part, int n) {
    __shared__ int s[256];
    int t = threadIdx.x;
    int v = (t < n) ? part[t] : 0;
    s[t] = v;
    __syncthreads();
    for (int d = 1; d < 256; d <<= 1) {
        int x = (t >= d) ? s[t - d] : 0;
        __syncthreads();
        s[t] += x;
        __syncthreads();
    }
    if (t < n) part[t] = s[t] - v;   // exclusive
}

__global__ void k_scan3(int* __restrict__ off, const int* __restrict__ part,
                        const int* __restrict__ deg, float* __restrict__ invdeg) {
    int i = blockIdx.x * blockDim.x + threadIdx.x;
    if (i == 0) off[NN] = NE;
    if (i < NN) {
        int o = off[i] + part[i >> 10];
        off[i] = o;
        int d = deg[i];
        invdeg[i] = 1.0f / (float)(d > 0 ? d : 1);
    }
}

// pass 2: coalesced ticket read, single random 4B csr write (no atomic)
__global__ void k_place(const unsigned long long* __restrict__ packed,
                        const int* __restrict__ off, int* __restrict__ csr) {
    int i = blockIdx.x * blockDim.x + threadIdx.x;
    int stride = gridDim.x * blockDim.x;
    for (int e = i; e < NE; e += stride) {
        unsigned long long p = packed[e];
        int s = (int)(p & 0x1FFFFu);
        int d = (int)((p >> 17) & 0x1FFFFu);
        int r = (int)(p >> 34);
        csr[off[d] + r] = s;
    }
}

// ---------------- mean aggregation: one wave per node ----------------
__global__ __launch_bounds__(256) void k_agg(const float* __restrict__ X,
                                             const int* __restrict__ off,
                                             const int* __restrict__ csr,
                                             const float* __restrict__ invdeg,
                                             float* __restrict__ M) {
    int wid = (blockIdx.x * 256 + threadIdx.x) >> 6;
    int lane = threadIdx.x & 63;
    if (wid >= NN) return;
    int s0 = off[wid], s1 = off[wid + 1];
    float ax = 0.f, ay = 0.f;
    int e = s0;
    for (; e + 1 < s1; e += 2) {
        int r0 = csr[e];
        int r1 = csr[e + 1];
        float2 v0 = *reinterpret_cast<const float2*>(X + (size_t)r0 * FD + lane * 2);
        float2 v1 = *reinterpret_cast<const float2*>(X + (size_t)r1 * FD + lane * 2);
        ax += v0.x + v1.x; ay += v0.y + v1.y;
    }
    if (e < s1) {
        int r = csr[e];
        float2 v = *reinterpret_cast<const float2*>(X + (size_t)r * FD + lane * 2);
        ax += v.x; ay += v.y;
    }
    float w = invdeg[wid];
    float2 o; o.x = ax * w; o.y = ay * w;
    *reinterpret_cast<float2*>(M + (size_t)wid * FD + lane * 2) = o;
}

// ---------------- split-bf16 MFMA helpers ----------------
__device__ inline void cvt_split(float v, unsigned short& h, unsigned short& l) {
    union { float f; unsigned u; } a; a.f = v;
    unsigned rh = (a.u + 0x7FFFu + ((a.u >> 16) & 1u)) >> 16;
    h = (unsigned short)rh;
    union { unsigned u; float f; } b; b.u = rh << 16;
    float lo = v - b.f;                       // exact (Sterbenz)
    union { float f; unsigned u; } c; c.f = lo;
    unsigned rl = (c.u + 0x7FFFu + ((c.u >> 16) & 1u)) >> 16;
    l = (unsigned short)rl;
}

// ---------------- dual GEMM via MFMA: out = relu(M@Wl^T + X@Wr^T + b) ------
// Block: 64 nodes x 128 outs. 4 waves, each 32 nodes x 64 outs
// = 2x4 tiles of mfma_f32_16x16x32_bf16. K=256 (concat M|X) in 8 chunks of 32.
// Split: out ~= Ah*Wh + Ah*Wl + Al*Wh  (rel err ~8e-6).
// M/out may alias across layers (block writes only its own fully-read rows).
__global__ __launch_bounds__(256, 3) void k_gemm(const float* M,
                                                 const float* __restrict__ X,
                                                 const float* __restrict__ Wl,
                                                 const float* __restrict__ Wr,
                                                 const float* __restrict__ bias,
                                                 float* out) {
    // rows padded to 40 halfwords (80B) -> 2-way bank aliasing only (free)
    __shared__ __align__(16) unsigned short Ah[64 * 40];
    __shared__ __align__(16) unsigned short Al[64 * 40];
    __shared__ __align__(16) unsigned short Bh[128 * 40];
    __shared__ __align__(16) unsigned short Bl[128 * 40];

    const int tid = threadIdx.x;
    const int wave = tid >> 6;
    const int lane = tid & 63;
    const int wm = wave & 1;        // node half (rows wm*32 ..)
    const int wn = wave >> 1;       // out half  (cols wn*64 ..)
    const int nb = blockIdx.x * 64;
    const int l15 = lane & 15;
    const int kb = lane >> 4;       // 0..3

    f32x4 acc[2][4] = {};

    for (int c = 0; c < 8; ++c) {
        const float* A = (c < 4) ? M : X;
        const float* W = (c < 4) ? Wl : Wr;
        const int kc = (c & 3) * 32;
        __syncthreads();
        // stage A chunk: 64 rows x 32 k  (512 float4 slots, 2/thread)
        {
            int slot = tid;
#pragma unroll
            for (int r = 0; r < 2; ++r, slot += 256) {
                int n = slot >> 3, q = slot & 7;
                int gn = nb + n;
                float4 v = make_float4(0.f, 0.f, 0.f, 0.f);
                if (gn < NN)
                    v = *reinterpret_cast<const float4*>(A + (size_t)gn * FD + kc + q * 4);
                unsigned short h0, h1, h2, h3, l0, l1, l2, l3;
                cvt_split(v.x, h0, l0); cvt_split(v.y, h1, l1);
                cvt_split(v.z, h2, l2); cvt_split(v.w, h3, l3);
                uint2 ph, pl;
                ph.x = (unsigned)h0 | ((unsigned)h1 << 16);
                ph.y = (unsigned)h2 | ((unsigned)h3 << 16);
                pl.x = (unsigned)l0 | ((unsigned)l1 << 16);
                pl.y = (unsigned)l2 | ((unsigned)l3 << 16);
                *reinterpret_cast<uint2*>(&Ah[n * 40 + q * 4]) = ph;
                *reinterpret_cast<uint2*>(&Al[n * 40 + q * 4]) = pl;
            }
        }
        // stage W chunk: 128 rows x 32 k (1024 slots, 4/thread)
        {
            int slot = tid;
#pragma unroll
            for (int r = 0; r < 4; ++r, slot += 256) {
                int o = slot >> 3, q = slot & 7;
                float4 v = *reinterpret_cast<const float4*>(W + o * FD + kc + q * 4);
                unsigned short h0, h1, h2, h3, l0, l1, l2, l3;
                cvt_split(v.x, h0, l0); cvt_split(v.y, h1, l1);
                cvt_split(v.z, h2, l2); cvt_split(v.w, h3, l3);
                uint2 ph, pl;
                ph.x = (unsigned)h0 | ((unsigned)h1 << 16);
                ph.y = (unsigned)h2 | ((unsigned)h3 << 16);
                pl.x = (unsigned)l0 | ((unsigned)l1 << 16);
                pl.y = (unsigned)l2 | ((unsigned)l3 << 16);
                *reinterpret_cast<uint2*>(&Bh[o * 40 + q * 4]) = ph;
                *reinterpret_cast<uint2*>(&Bl[o * 40 + q * 4]) = pl;
            }
        }
        __syncthreads();
        // fragments: A lane: row = l15, k = kb*8..+7 ; B lane: col = l15, same k
        short8 a_h[2], a_l[2], b_h[4], b_l[4];
#pragma unroll
        for (int mt = 0; mt < 2; ++mt) {
            int row = wm * 32 + mt * 16 + l15;
            a_h[mt] = *reinterpret_cast<const short8*>(&Ah[row * 40 + kb * 8]);
            a_l[mt] = *reinterpret_cast<const short8*>(&Al[row * 40 + kb * 8]);
        }
#pragma unroll
        for (int nt = 0; nt < 4; ++nt) {
            int o = wn * 64 + nt * 16 + l15;
            b_h[nt] = *reinterpret_cast<const short8*>(&Bh[o * 40 + kb * 8]);
            b_l[nt] = *reinterpret_cast<const short8*>(&Bl[o * 40 + kb * 8]);
        }
#pragma unroll
        for (int mt = 0; mt < 2; ++mt)
#pragma unroll
            for (int nt = 0; nt < 4; ++nt) {
                acc[mt][nt] = __builtin_amdgcn_mfma_f32_16x16x32_bf16(a_h[mt], b_h[nt], acc[mt][nt], 0, 0, 0);
                acc[mt][nt] = __builtin_amdgcn_mfma_f32_16x16x32_bf16(a_h[mt], b_l[nt], acc[mt][nt], 0, 0, 0);
                acc[mt][nt] = __builtin_amdgcn_mfma_f32_16x16x32_bf16(a_l[mt], b_h[nt], acc[mt][nt], 0, 0, 0);
            }
    }

    // epilogue: C/D layout col = lane&15, row = (lane>>4)*4 + r
    float bz[4];
#pragma unroll
    for (int nt = 0; nt < 4; ++nt) bz[nt] = bias[wn * 64 + nt * 16 + l15];
#pragma unroll
    for (int mt = 0; mt < 2; ++mt) {
        int gn0 = nb + wm * 32 + mt * 16 + kb * 4;
#pragma unroll
        for (int r = 0; r < 4; ++r) {
            int gn = gn0 + r;
            if (gn < NN) {
#pragma unroll
                for (int nt = 0; nt < 4; ++nt) {
                    float v = fmaxf(acc[mt][nt][r] + bz[nt], 0.f);
                    out[(size_t)gn * FD + wn * 64 + nt * 16 + l15] = v;
                }
            }
        }
    }
}

// ---------------- classifier: out = H @ Wc^T + bc ----------------
__global__ __launch_bounds__(256) void k_cls(const float* __restrict__ H,
                                             const float* __restrict__ Wc,
                                             const float* __restrict__ bc,
                                             float* __restrict__ out) {
    __shared__ __align__(16) float Wcs[40 * 132];
    const int tid = threadIdx.x;
#pragma unroll
    for (int r = 0; r < 5; ++r) {
        int slot = tid + 256 * r;      // < 1280
        int cls = slot >> 5;
        int c4 = slot & 31;
        float4 v = *reinterpret_cast<const float4*>(Wc + cls * FD + c4 * 4);
        *reinterpret_cast<float4*>(&Wcs[cls * 132 + c4 * 4]) = v;
    }
    __syncthreads();
    const int tx = tid & 7;      // cls = tx*5 + j
    const int ty = tid >> 3;     // node = nb + ty*2 + i
    const int nb = blockIdx.x * 64;
    const int n0 = nb + ty * 2;
    const int n1 = n0 + 1;
    const bool v0 = n0 < NN, v1 = n1 < NN;
    float acc[2][5] = {};
#pragma unroll 4
    for (int k = 0; k < FD; k += 4) {
        float4 h0 = v0 ? *reinterpret_cast<const float4*>(H + (size_t)n0 * FD + k)
                       : make_float4(0.f, 0.f, 0.f, 0.f);
        float4 h1 = v1 ? *reinterpret_cast<const float4*>(H + (size_t)n1 * FD + k)
                       : make_float4(0.f, 0.f, 0.f, 0.f);
#pragma unroll
        for (int j = 0; j < 5; ++j) {
            float4 w = *reinterpret_cast<const float4*>(&Wcs[(tx * 5 + j) * 132 + k]);
            acc[0][j] += h0.x * w.x + h0.y * w.y + h0.z * w.z + h0.w * w.w;
            acc[1][j] += h1.x * w.x + h1.y * w.y + h1.z * w.z + h1.w * w.w;
        }
    }
    if (v0) {
#pragma unroll
        for (int j = 0; j < 5; ++j)
            out[(size_t)n0 * NC + tx * 5 + j] = acc[0][j] + bc[tx * 5 + j];
    }
    if (v1) {
#pragma unroll
        for (int j = 0; j < 5; ++j)
            out[(size_t)n1 * NC + tx * 5 + j] = acc[1][j] + bc[tx * 5 + j];
    }
}

extern "C" void kernel_launch(void* const* d_in, const int* in_sizes, int n_in,
                              void* d_out, int out_size, void* d_ws, size_t ws_size,
                              hipStream_t stream) {
    const float* x   = (const float*)d_in[0];
    const int*   ei  = (const int*)d_in[1];
    const float* W1l = (const float*)d_in[3];
    const float* b1l = (const float*)d_in[4];
    const float* W1r = (const float*)d_in[5];
    const float* W2l = (const float*)d_in[6];
    const float* b2l = (const float*)d_in[7];
    const float* W2r = (const float*)d_in[8];
    const float* Wc  = (const float*)d_in[9];
    const float* bc  = (const float*)d_in[10];
    float* out = (float*)d_out;

    char* ws = (char*)d_ws;
    int*   deg    = (int*)(ws + WS_DEG);
    int*   off    = (int*)(ws + WS_OFF);
    float* invdeg = (float*)(ws + WS_INVDEG);
    int*   part   = (int*)(ws + WS_PART);
    int*   csr    = (int*)(ws + WS_CSR);
    float* mean   = (float*)(ws + WS_MEAN);
    float* h      = (float*)(ws + WS_H);
    unsigned long long* packed = (unsigned long long*)(ws + WS_H); // consumed before h written

    hipMemsetAsync(deg, 0, NN * sizeof(int), stream);
    k_ticket<<<2048, 256, 0, stream>>>(ei, deg, packed);
    int G1 = (NN + 1023) / 1024;  // 98
    k_scan1<<<G1, 256, 0, stream>>>(deg, off, part);
    k_scan2<<<1, 256, 0, stream>>>(part, G1);
    k_scan3<<<(NN + 255) / 256, 256, 0, stream>>>(off, part, deg, invdeg);
    k_place<<<2048, 256, 0, stream>>>(packed, off, csr);

    const int GG = (NN + 63) / 64;   // 1563

    // layer 1
    k_agg<<<(NN + 3) / 4, 256, 0, stream>>>(x, off, csr, invdeg, mean);
    k_gemm<<<GG, 256, 0, stream>>>(mean, x, W1l, W1r, b1l, h);
    // layer 2 (h2 overwrites mean: each block touches only its own rows)
    k_agg<<<(NN + 3) / 4, 256, 0, stream>>>(h, off, csr, invdeg, mean);
    k_gemm<<<GG, 256, 0, stream>>>(mean, h, W2l, W2r, b2l, mean);
    // classifier
    k_cls<<<GG, 256, 0, stream>>>(mean, Wc, bc, out);
}

// Round 4
// 384.385 us; speedup vs baseline: 3.8970x; 1.2032x over previous
//
#include <hip/hip_runtime.h>

#define NN 100000
#define NE 1600000
#define FD 128
#define NC 40

typedef __attribute__((ext_vector_type(8))) short short8;
typedef __attribute__((ext_vector_type(4))) float f32x4;

// ---- workspace layout (bytes) ----
#define WS_DEG      0u
#define WS_OFF      401408u
#define WS_INVDEG   802816u
#define WS_PART     1204224u
#define WS_CSR      1205248u      // E int (6.4 MB)
#define WS_XB       7605248u      // N*128 bf16 (25.6 MB)
#define WS_MEAN     33205248u     // N*128 bf16 (25.6 MB) - mean (both layers)
#define WS_H        58805248u     // N*128 bf16 h1; doubles as packed u64[NE] during CSR build

__device__ inline unsigned short bf16_rne(float v) {
    union { float f; unsigned u; } a; a.f = v;
    return (unsigned short)((a.u + 0x7FFFu + ((a.u >> 16) & 1u)) >> 16);
}

__device__ inline void cvt_split(float v, unsigned short& h, unsigned short& l) {
    union { float f; unsigned u; } a; a.f = v;
    unsigned rh = (a.u + 0x7FFFu + ((a.u >> 16) & 1u)) >> 16;
    h = (unsigned short)rh;
    union { unsigned u; float f; } b; b.u = rh << 16;
    float lo = v - b.f;
    union { float f; unsigned u; } c; c.f = lo;
    l = (unsigned short)((c.u + 0x7FFFu + ((c.u >> 16) & 1u)) >> 16);
}

// ---------------- CSR build ----------------
__global__ void k_ticket(const int* __restrict__ ei, int* __restrict__ deg,
                         unsigned long long* __restrict__ packed) {
    int i = blockIdx.x * blockDim.x + threadIdx.x;
    int stride = gridDim.x * blockDim.x;
    for (int e = i; e < NE; e += stride) {
        int s = ei[e];
        int d = ei[NE + e];
        unsigned r = atomicAdd(&deg[d], 1);
        packed[e] = (unsigned long long)(unsigned)s |
                    ((unsigned long long)(unsigned)d << 17) |
                    ((unsigned long long)r << 34);
    }
}

__global__ void k_scan1(const int* __restrict__ deg, int* __restrict__ off,
                        int* __restrict__ part) {
    __shared__ int s[256];
    int t = threadIdx.x;
    int base = blockIdx.x * 1024 + t * 4;
    int v[4]; int tsum = 0;
#pragma unroll
    for (int j = 0; j < 4; ++j) {
        int idx = base + j;
        v[j] = (idx < NN) ? deg[idx] : 0;
        tsum += v[j];
    }
    s[t] = tsum;
    __syncthreads();
    for (int d = 1; d < 256; d <<= 1) {
        int x = (t >= d) ? s[t - d] : 0;
        __syncthreads();
        s[t] += x;
        __syncthreads();
    }
    int excl = s[t] - tsum;
    if (t == 255) part[blockIdx.x] = s[t];
    int p = excl;
#pragma unroll
    for (int j = 0; j < 4; ++j) {
        int idx = base + j;
        if (idx < NN) off[idx] = p;
        p += v[j];
    }
}

__global__ void k_scan2(int* __restrict__ part, int n) {
    __shared__ int s[256];
    int t = threadIdx.x;
    int v = (t < n) ? part[t] : 0;
    s[t] = v;
    __syncthreads();
    for (int d = 1; d < 256; d <<= 1) {
        int x = (t >= d) ? s[t - d] : 0;
        __syncthreads();
        s[t] += x;
        __syncthreads();
    }
    if (t < n) part[t] = s[t] - v;
}

__global__ void k_scan3(int* __restrict__ off, const int* __restrict__ part,
                        const int* __restrict__ deg, float* __restrict__ invdeg) {
    int i = blockIdx.x * blockDim.x + threadIdx.x;
    if (i == 0) off[NN] = NE;
    if (i < NN) {
        int o = off[i] + part[i >> 10];
        off[i] = o;
        int d = deg[i];
        invdeg[i] = 1.0f / (float)(d > 0 ? d : 1);
    }
}

__global__ void k_place(const unsigned long long* __restrict__ packed,
                        const int* __restrict__ off, int* __restrict__ csr) {
    int i = blockIdx.x * blockDim.x + threadIdx.x;
    int stride = gridDim.x * blockDim.x;
    for (int e = i; e < NE; e += stride) {
        unsigned long long p = packed[e];
        int s = (int)(p & 0x1FFFFu);
        int d = (int)((p >> 17) & 0x1FFFFu);
        int r = (int)(p >> 34);
        csr[off[d] + r] = s;
    }
}

// ---------------- f32 -> bf16 convert ----------------
__global__ void k_tobf16(const float* __restrict__ x, unsigned short* __restrict__ xb) {
    int i = blockIdx.x * blockDim.x + threadIdx.x;
    int stride = gridDim.x * blockDim.x;
    const int total = NN * FD / 8;
    for (int s = i; s < total; s += stride) {
        float4 a = *reinterpret_cast<const float4*>(x + (size_t)s * 8);
        float4 b = *reinterpret_cast<const float4*>(x + (size_t)s * 8 + 4);
        short8 o;
        o[0] = (short)bf16_rne(a.x); o[1] = (short)bf16_rne(a.y);
        o[2] = (short)bf16_rne(a.z); o[3] = (short)bf16_rne(a.w);
        o[4] = (short)bf16_rne(b.x); o[5] = (short)bf16_rne(b.y);
        o[6] = (short)bf16_rne(b.z); o[7] = (short)bf16_rne(b.w);
        *reinterpret_cast<short8*>(xb + (size_t)s * 8) = o;
    }
}

// ---------------- mean aggregation: one wave per node, bf16 ----------------
__global__ __launch_bounds__(256) void k_agg(const unsigned short* __restrict__ Xb,
                                             const int* __restrict__ off,
                                             const int* __restrict__ csr,
                                             const float* __restrict__ invdeg,
                                             unsigned short* __restrict__ Mb) {
    int wid = (blockIdx.x * 256 + threadIdx.x) >> 6;
    int lane = threadIdx.x & 63;
    if (wid >= NN) return;
    int s0 = off[wid], s1 = off[wid + 1];
    float ax = 0.f, ay = 0.f;
    int e = s0;
    for (; e + 1 < s1; e += 2) {
        int r0 = csr[e], r1 = csr[e + 1];
        unsigned v0 = *reinterpret_cast<const unsigned*>(Xb + (size_t)r0 * FD + lane * 2);
        unsigned v1 = *reinterpret_cast<const unsigned*>(Xb + (size_t)r1 * FD + lane * 2);
        ax += __uint_as_float(v0 << 16) + __uint_as_float(v1 << 16);
        ay += __uint_as_float(v0 & 0xFFFF0000u) + __uint_as_float(v1 & 0xFFFF0000u);
    }
    if (e < s1) {
        int r = csr[e];
        unsigned v = *reinterpret_cast<const unsigned*>(Xb + (size_t)r * FD + lane * 2);
        ax += __uint_as_float(v << 16);
        ay += __uint_as_float(v & 0xFFFF0000u);
    }
    float w = invdeg[wid];
    unsigned o = (unsigned)bf16_rne(ax * w) | ((unsigned)bf16_rne(ay * w) << 16);
    *reinterpret_cast<unsigned*>(Mb + (size_t)wid * FD + lane * 2) = o;
}

// ---------------- dual GEMM via MFMA (+fused classifier) ----------------
// h = relu(M@Wl^T + X@Wr^T + b); M,X bf16; W split hi/lo (a*(Wh+Wl)).
// FUSE=false: write h bf16 [N][128].
// FUSE=true : h2 tile -> LDS bf16, out = h2 @ Wc^T + bc, write f32 [N][40].
template <bool FUSE>
__global__ __launch_bounds__(256, 3) void k_gemm(
        const unsigned short* __restrict__ M,
        const unsigned short* __restrict__ X,
        const float* __restrict__ Wl,
        const float* __restrict__ Wr,
        const float* __restrict__ bias,
        const float* __restrict__ Wc,
        const float* __restrict__ bc,
        unsigned short* outb, float* outf) {
    __shared__ __align__(16) unsigned short pool[FUSE ? 21504 : 12800];
    unsigned short* Ah = pool;            // [64][40]
    unsigned short* Bh = pool + 2560;     // [128][40]
    unsigned short* Bl = pool + 7680;     // [128][40]

    const int tid = threadIdx.x;
    const int wave = tid >> 6;
    const int lane = tid & 63;
    const int wm = wave & 1;        // node half
    const int wn = wave >> 1;       // out half
    const int nb = blockIdx.x * 64;
    const int l15 = lane & 15;
    const int kb = lane >> 4;

    f32x4 acc[2][4] = {};

    for (int c = 0; c < 8; ++c) {
        const unsigned short* A = (c < 4) ? M : X;
        const float* W = (c < 4) ? Wl : Wr;
        const int kc = (c & 3) * 32;
        __syncthreads();
        // A chunk 64x32 bf16: row = tid>>2, seg = tid&3 (8 elems)
        {
            int row = tid >> 2, seg = tid & 3;
            int gn = nb + row;
            short8 v = {};
            if (gn < NN)
                v = *reinterpret_cast<const short8*>(A + (size_t)gn * FD + kc + seg * 8);
            *reinterpret_cast<short8*>(&Ah[row * 40 + seg * 8]) = v;
        }
        // B chunk 128x32 f32 -> split hi/lo
#pragma unroll
        for (int r = 0; r < 4; ++r) {
            int slot = tid + 256 * r;
            int o = slot >> 3, q = slot & 7;
            float4 v = *reinterpret_cast<const float4*>(W + o * FD + kc + q * 4);
            unsigned short h0, h1, h2, h3, l0, l1, l2, l3;
            cvt_split(v.x, h0, l0); cvt_split(v.y, h1, l1);
            cvt_split(v.z, h2, l2); cvt_split(v.w, h3, l3);
            uint2 ph, pl;
            ph.x = (unsigned)h0 | ((unsigned)h1 << 16);
            ph.y = (unsigned)h2 | ((unsigned)h3 << 16);
            pl.x = (unsigned)l0 | ((unsigned)l1 << 16);
            pl.y = (unsigned)l2 | ((unsigned)l3 << 16);
            *reinterpret_cast<uint2*>(&Bh[o * 40 + q * 4]) = ph;
            *reinterpret_cast<uint2*>(&Bl[o * 40 + q * 4]) = pl;
        }
        __syncthreads();
        short8 a[2], b_h[4], b_l[4];
#pragma unroll
        for (int mt = 0; mt < 2; ++mt) {
            int row = wm * 32 + mt * 16 + l15;
            a[mt] = *reinterpret_cast<const short8*>(&Ah[row * 40 + kb * 8]);
        }
#pragma unroll
        for (int nt = 0; nt < 4; ++nt) {
            int o = wn * 64 + nt * 16 + l15;
            b_h[nt] = *reinterpret_cast<const short8*>(&Bh[o * 40 + kb * 8]);
            b_l[nt] = *reinterpret_cast<const short8*>(&Bl[o * 40 + kb * 8]);
        }
#pragma unroll
        for (int mt = 0; mt < 2; ++mt)
#pragma unroll
            for (int nt = 0; nt < 4; ++nt) {
                acc[mt][nt] = __builtin_amdgcn_mfma_f32_16x16x32_bf16(a[mt], b_h[nt], acc[mt][nt], 0, 0, 0);
                acc[mt][nt] = __builtin_amdgcn_mfma_f32_16x16x32_bf16(a[mt], b_l[nt], acc[mt][nt], 0, 0, 0);
            }
    }

    float bz[4];
#pragma unroll
    for (int nt = 0; nt < 4; ++nt) bz[nt] = bias[wn * 64 + nt * 16 + l15];

    if (!FUSE) {
        // write h bf16; C/D layout: col = l15, row = kb*4 + r
#pragma unroll
        for (int mt = 0; mt < 2; ++mt) {
            int gn0 = nb + wm * 32 + mt * 16 + kb * 4;
#pragma unroll
            for (int r = 0; r < 4; ++r) {
                int gn = gn0 + r;
                if (gn < NN) {
#pragma unroll
                    for (int nt = 0; nt < 4; ++nt) {
                        float v = fmaxf(acc[mt][nt][r] + bz[nt], 0.f);
                        outb[(size_t)gn * FD + wn * 64 + nt * 16 + l15] = bf16_rne(v);
                    }
                }
            }
        }
    } else {
        unsigned short* Hs  = pool + 12800;   // [64][136]
        unsigned short* Wcs = pool;           // [48][136] (reuses staging, 6528 <= 12800)
        __syncthreads();  // all waves done reading Bh/Bl
        // stage Wc bf16 (rows 40..47 read as garbage but never stored)
#pragma unroll
        for (int r = 0; r < 5; ++r) {
            int slot = tid + 256 * r;
            int cls = slot >> 5, q = slot & 31;
            float4 v = *reinterpret_cast<const float4*>(Wc + cls * FD + q * 4);
            uint2 p;
            p.x = (unsigned)bf16_rne(v.x) | ((unsigned)bf16_rne(v.y) << 16);
            p.y = (unsigned)bf16_rne(v.z) | ((unsigned)bf16_rne(v.w) << 16);
            *reinterpret_cast<uint2*>(&Wcs[cls * 136 + q * 4]) = p;
        }
        // stage h2 quadrant (relu + bf16)
#pragma unroll
        for (int mt = 0; mt < 2; ++mt) {
            int row0 = wm * 32 + mt * 16 + kb * 4;
#pragma unroll
            for (int r = 0; r < 4; ++r) {
#pragma unroll
                for (int nt = 0; nt < 4; ++nt) {
                    float v = fmaxf(acc[mt][nt][r] + bz[nt], 0.f);
                    Hs[(row0 + r) * 136 + wn * 64 + nt * 16 + l15] = bf16_rne(v);
                }
            }
        }
        __syncthreads();
        // mini-GEMM: wave w -> rows w*16..+15, cols 0..47 (3 tiles), K=128
        f32x4 c2[3] = {};
#pragma unroll
        for (int kk = 0; kk < 4; ++kk) {
            short8 af = *reinterpret_cast<const short8*>(
                &Hs[(wave * 16 + l15) * 136 + kk * 32 + kb * 8]);
#pragma unroll
            for (int t = 0; t < 3; ++t) {
                short8 bf = *reinterpret_cast<const short8*>(
                    &Wcs[(t * 16 + l15) * 136 + kk * 32 + kb * 8]);
                c2[t] = __builtin_amdgcn_mfma_f32_16x16x32_bf16(af, bf, c2[t], 0, 0, 0);
            }
        }
#pragma unroll
        for (int t = 0; t < 3; ++t) {
            int cls = t * 16 + l15;
            if (cls < NC) {
#pragma unroll
                for (int r = 0; r < 4; ++r) {
                    int gn = nb + wave * 16 + kb * 4 + r;
                    if (gn < NN)
                        outf[(size_t)gn * NC + cls] = c2[t][r] + bc[cls];
                }
            }
        }
    }
}

extern "C" void kernel_launch(void* const* d_in, const int* in_sizes, int n_in,
                              void* d_out, int out_size, void* d_ws, size_t ws_size,
                              hipStream_t stream) {
    const float* x   = (const float*)d_in[0];
    const int*   ei  = (const int*)d_in[1];
    const float* W1l = (const float*)d_in[3];
    const float* b1l = (const float*)d_in[4];
    const float* W1r = (const float*)d_in[5];
    const float* W2l = (const float*)d_in[6];
    const float* b2l = (const float*)d_in[7];
    const float* W2r = (const float*)d_in[8];
    const float* Wc  = (const float*)d_in[9];
    const float* bc  = (const float*)d_in[10];
    float* out = (float*)d_out;

    char* ws = (char*)d_ws;
    int*   deg    = (int*)(ws + WS_DEG);
    int*   off    = (int*)(ws + WS_OFF);
    float* invdeg = (float*)(ws + WS_INVDEG);
    int*   part   = (int*)(ws + WS_PART);
    int*   csr    = (int*)(ws + WS_CSR);
    unsigned short* xb = (unsigned short*)(ws + WS_XB);
    unsigned short* mb = (unsigned short*)(ws + WS_MEAN);
    unsigned short* hb = (unsigned short*)(ws + WS_H);
    unsigned long long* packed = (unsigned long long*)(ws + WS_H); // consumed before hb written

    hipMemsetAsync(deg, 0, NN * sizeof(int), stream);
    k_tobf16<<<2048, 256, 0, stream>>>(x, xb);
    k_ticket<<<2048, 256, 0, stream>>>(ei, deg, packed);
    int G1 = (NN + 1023) / 1024;  // 98
    k_scan1<<<G1, 256, 0, stream>>>(deg, off, part);
    k_scan2<<<1, 256, 0, stream>>>(part, G1);
    k_scan3<<<(NN + 255) / 256, 256, 0, stream>>>(off, part, deg, invdeg);
    k_place<<<2048, 256, 0, stream>>>(packed, off, csr);

    const int GG = (NN + 63) / 64;   // 1563

    // layer 1
    k_agg<<<(NN + 3) / 4, 256, 0, stream>>>(xb, off, csr, invdeg, mb);
    k_gemm<false><<<GG, 256, 0, stream>>>(mb, xb, W1l, W1r, b1l,
                                          nullptr, nullptr, hb, nullptr);
    // layer 2 + fused classifier
    k_agg<<<(NN + 3) / 4, 256, 0, stream>>>(hb, off, csr, invdeg, mb);
    k_gemm<true><<<GG, 256, 0, stream>>>(mb, hb, W2l, W2r, b2l,
                                         Wc, bc, nullptr, out);
}

// Round 5
// 344.803 us; speedup vs baseline: 4.3443x; 1.1148x over previous
//
#include <hip/hip_runtime.h>

#define NN 100000
#define NE 1600000
#define FD 128
#define NC 40

typedef __attribute__((ext_vector_type(8))) short short8;
typedef __attribute__((ext_vector_type(4))) float f32x4;

// ---- workspace layout (bytes) ----
#define WS_DEG      0u
#define WS_OFF      401408u
#define WS_INVDEG   802816u
#define WS_PART     1204224u
#define WS_CSR      1205248u      // E int (6.4 MB)
#define WS_XB       7605248u      // N*128 bf16 (25.6 MB)
#define WS_MEAN     33205248u     // N*128 bf16 (25.6 MB) - mean (both layers)
#define WS_H        58805248u     // N*128 bf16 h1; doubles as u32 ticket[NE] during CSR build

__device__ inline unsigned short bf16_rne(float v) {
    union { float f; unsigned u; } a; a.f = v;
    return (unsigned short)((a.u + 0x7FFFu + ((a.u >> 16) & 1u)) >> 16);
}

__device__ inline void cvt_split(float v, unsigned short& h, unsigned short& l) {
    union { float f; unsigned u; } a; a.f = v;
    unsigned rh = (a.u + 0x7FFFu + ((a.u >> 16) & 1u)) >> 16;
    h = (unsigned short)rh;
    union { unsigned u; float f; } b; b.u = rh << 16;
    float lo = v - b.f;
    union { float f; unsigned u; } c; c.f = lo;
    l = (unsigned short)((c.u + 0x7FFFu + ((c.u >> 16) & 1u)) >> 16);
}

// ---------------- CSR build ----------------
// pass 1: rank ticket (one atomic pass), u32 packed = src | rank<<17
__global__ void k_ticket(const int* __restrict__ ei, int* __restrict__ deg,
                         unsigned* __restrict__ packed) {
    int i = blockIdx.x * blockDim.x + threadIdx.x;
    int stride = gridDim.x * blockDim.x;
    for (int e = i; e < NE; e += stride) {
        int s = ei[e];
        int d = ei[NE + e];
        unsigned r = atomicAdd(&deg[d], 1);
        __builtin_nontemporal_store((unsigned)s | (r << 17), &packed[e]);
    }
}

__global__ void k_scan1(const int* __restrict__ deg, int* __restrict__ off,
                        int* __restrict__ part) {
    __shared__ int s[256];
    int t = threadIdx.x;
    int base = blockIdx.x * 1024 + t * 4;
    int v[4]; int tsum = 0;
#pragma unroll
    for (int j = 0; j < 4; ++j) {
        int idx = base + j;
        v[j] = (idx < NN) ? deg[idx] : 0;
        tsum += v[j];
    }
    s[t] = tsum;
    __syncthreads();
    for (int d = 1; d < 256; d <<= 1) {
        int x = (t >= d) ? s[t - d] : 0;
        __syncthreads();
        s[t] += x;
        __syncthreads();
    }
    int excl = s[t] - tsum;
    if (t == 255) part[blockIdx.x] = s[t];
    int p = excl;
#pragma unroll
    for (int j = 0; j < 4; ++j) {
        int idx = base + j;
        if (idx < NN) off[idx] = p;
        p += v[j];
    }
}

__global__ void k_scan2(int* __restrict__ part, int n) {
    __shared__ int s[256];
    int t = threadIdx.x;
    int v = (t < n) ? part[t] : 0;
    s[t] = v;
    __syncthreads();
    for (int d = 1; d < 256; d <<= 1) {
        int x = (t >= d) ? s[t - d] : 0;
        __syncthreads();
        s[t] += x;
        __syncthreads();
    }
    if (t < n) part[t] = s[t] - v;
}

__global__ void k_scan3(int* __restrict__ off, const int* __restrict__ part,
                        const int* __restrict__ deg, float* __restrict__ invdeg) {
    int i = blockIdx.x * blockDim.x + threadIdx.x;
    if (i == 0) off[NN] = NE;
    if (i < NN) {
        int o = off[i] + part[i >> 10];
        off[i] = o;
        int d = deg[i];
        invdeg[i] = 1.0f / (float)(d > 0 ? d : 1);
    }
}

// pass 2: coalesced ticket+dst read, single random 4B csr write (no atomic)
__global__ void k_place(const unsigned* __restrict__ packed,
                        const int* __restrict__ dst,
                        const int* __restrict__ off, int* __restrict__ csr) {
    int i = blockIdx.x * blockDim.x + threadIdx.x;
    int stride = gridDim.x * blockDim.x;
    for (int e = i; e < NE; e += stride) {
        unsigned p = __builtin_nontemporal_load(&packed[e]);
        int d = dst[e];
        csr[off[d] + (int)(p >> 17)] = (int)(p & 0x1FFFFu);
    }
}

// ---------------- f32 -> bf16 convert ----------------
__global__ void k_tobf16(const float* __restrict__ x, unsigned short* __restrict__ xb) {
    int i = blockIdx.x * blockDim.x + threadIdx.x;
    int stride = gridDim.x * blockDim.x;
    const int total = NN * FD / 8;
    for (int s = i; s < total; s += stride) {
        float4 a = *reinterpret_cast<const float4*>(x + (size_t)s * 8);
        float4 b = *reinterpret_cast<const float4*>(x + (size_t)s * 8 + 4);
        short8 o;
        o[0] = (short)bf16_rne(a.x); o[1] = (short)bf16_rne(a.y);
        o[2] = (short)bf16_rne(a.z); o[3] = (short)bf16_rne(a.w);
        o[4] = (short)bf16_rne(b.x); o[5] = (short)bf16_rne(b.y);
        o[6] = (short)bf16_rne(b.z); o[7] = (short)bf16_rne(b.w);
        *reinterpret_cast<short8*>(xb + (size_t)s * 8) = o;
    }
}

// ---------------- mean aggregation: one wave per node, bf16, 4-deep MLP ----
__global__ __launch_bounds__(256) void k_agg(const unsigned short* __restrict__ Xb,
                                             const int* __restrict__ off,
                                             const int* __restrict__ csr,
                                             const float* __restrict__ invdeg,
                                             unsigned short* __restrict__ Mb) {
    int wid = (blockIdx.x * 256 + threadIdx.x) >> 6;
    int lane = threadIdx.x & 63;
    if (wid >= NN) return;
    int s0 = off[wid], s1 = off[wid + 1];
    const unsigned short* Xl = Xb + lane * 2;
    float ax = 0.f, ay = 0.f;
    int e = s0;
    for (; e + 3 < s1; e += 4) {
        int r0 = csr[e], r1 = csr[e + 1], r2 = csr[e + 2], r3 = csr[e + 3];
        unsigned v0 = *reinterpret_cast<const unsigned*>(Xl + ((size_t)r0 << 7));
        unsigned v1 = *reinterpret_cast<const unsigned*>(Xl + ((size_t)r1 << 7));
        unsigned v2 = *reinterpret_cast<const unsigned*>(Xl + ((size_t)r2 << 7));
        unsigned v3 = *reinterpret_cast<const unsigned*>(Xl + ((size_t)r3 << 7));
        ax += __uint_as_float(v0 << 16); ay += __uint_as_float(v0 & 0xFFFF0000u);
        ax += __uint_as_float(v1 << 16); ay += __uint_as_float(v1 & 0xFFFF0000u);
        ax += __uint_as_float(v2 << 16); ay += __uint_as_float(v2 & 0xFFFF0000u);
        ax += __uint_as_float(v3 << 16); ay += __uint_as_float(v3 & 0xFFFF0000u);
    }
    for (; e < s1; ++e) {
        int r = csr[e];
        unsigned v = *reinterpret_cast<const unsigned*>(Xl + ((size_t)r << 7));
        ax += __uint_as_float(v << 16);
        ay += __uint_as_float(v & 0xFFFF0000u);
    }
    float w = invdeg[wid];
    unsigned o = (unsigned)bf16_rne(ax * w) | ((unsigned)bf16_rne(ay * w) << 16);
    *reinterpret_cast<unsigned*>(Mb + (size_t)wid * FD + lane * 2) = o;
}

// ---------------- dual GEMM via MFMA (+fused classifier) ----------------
template <bool FUSE>
__global__ __launch_bounds__(256, 3) void k_gemm(
        const unsigned short* __restrict__ M,
        const unsigned short* __restrict__ X,
        const float* __restrict__ Wl,
        const float* __restrict__ Wr,
        const float* __restrict__ bias,
        const float* __restrict__ Wc,
        const float* __restrict__ bc,
        unsigned short* outb, float* outf) {
    __shared__ __align__(16) unsigned short pool[FUSE ? 21504 : 12800];
    unsigned short* Ah = pool;            // [64][40]
    unsigned short* Bh = pool + 2560;     // [128][40]
    unsigned short* Bl = pool + 7680;     // [128][40]

    const int tid = threadIdx.x;
    const int wave = tid >> 6;
    const int lane = tid & 63;
    const int wm = wave & 1;
    const int wn = wave >> 1;
    const int nb = blockIdx.x * 64;
    const int l15 = lane & 15;
    const int kb = lane >> 4;

    f32x4 acc[2][4] = {};

    for (int c = 0; c < 8; ++c) {
        const unsigned short* A = (c < 4) ? M : X;
        const float* W = (c < 4) ? Wl : Wr;
        const int kc = (c & 3) * 32;
        __syncthreads();
        {
            int row = tid >> 2, seg = tid & 3;
            int gn = nb + row;
            short8 v = {};
            if (gn < NN)
                v = *reinterpret_cast<const short8*>(A + (size_t)gn * FD + kc + seg * 8);
            *reinterpret_cast<short8*>(&Ah[row * 40 + seg * 8]) = v;
        }
#pragma unroll
        for (int r = 0; r < 4; ++r) {
            int slot = tid + 256 * r;
            int o = slot >> 3, q = slot & 7;
            float4 v = *reinterpret_cast<const float4*>(W + o * FD + kc + q * 4);
            unsigned short h0, h1, h2, h3, l0, l1, l2, l3;
            cvt_split(v.x, h0, l0); cvt_split(v.y, h1, l1);
            cvt_split(v.z, h2, l2); cvt_split(v.w, h3, l3);
            uint2 ph, pl;
            ph.x = (unsigned)h0 | ((unsigned)h1 << 16);
            ph.y = (unsigned)h2 | ((unsigned)h3 << 16);
            pl.x = (unsigned)l0 | ((unsigned)l1 << 16);
            pl.y = (unsigned)l2 | ((unsigned)l3 << 16);
            *reinterpret_cast<uint2*>(&Bh[o * 40 + q * 4]) = ph;
            *reinterpret_cast<uint2*>(&Bl[o * 40 + q * 4]) = pl;
        }
        __syncthreads();
        short8 a[2], b_h[4], b_l[4];
#pragma unroll
        for (int mt = 0; mt < 2; ++mt) {
            int row = wm * 32 + mt * 16 + l15;
            a[mt] = *reinterpret_cast<const short8*>(&Ah[row * 40 + kb * 8]);
        }
#pragma unroll
        for (int nt = 0; nt < 4; ++nt) {
            int o = wn * 64 + nt * 16 + l15;
            b_h[nt] = *reinterpret_cast<const short8*>(&Bh[o * 40 + kb * 8]);
            b_l[nt] = *reinterpret_cast<const short8*>(&Bl[o * 40 + kb * 8]);
        }
#pragma unroll
        for (int mt = 0; mt < 2; ++mt)
#pragma unroll
            for (int nt = 0; nt < 4; ++nt) {
                acc[mt][nt] = __builtin_amdgcn_mfma_f32_16x16x32_bf16(a[mt], b_h[nt], acc[mt][nt], 0, 0, 0);
                acc[mt][nt] = __builtin_amdgcn_mfma_f32_16x16x32_bf16(a[mt], b_l[nt], acc[mt][nt], 0, 0, 0);
            }
    }

    float bz[4];
#pragma unroll
    for (int nt = 0; nt < 4; ++nt) bz[nt] = bias[wn * 64 + nt * 16 + l15];

    if (!FUSE) {
#pragma unroll
        for (int mt = 0; mt < 2; ++mt) {
            int gn0 = nb + wm * 32 + mt * 16 + kb * 4;
#pragma unroll
            for (int r = 0; r < 4; ++r) {
                int gn = gn0 + r;
                if (gn < NN) {
#pragma unroll
                    for (int nt = 0; nt < 4; ++nt) {
                        float v = fmaxf(acc[mt][nt][r] + bz[nt], 0.f);
                        outb[(size_t)gn * FD + wn * 64 + nt * 16 + l15] = bf16_rne(v);
                    }
                }
            }
        }
    } else {
        unsigned short* Hs  = pool + 12800;   // [64][136]
        unsigned short* Wcs = pool;           // [48][136]
        __syncthreads();
#pragma unroll
        for (int r = 0; r < 5; ++r) {
            int slot = tid + 256 * r;
            int cls = slot >> 5, q = slot & 31;
            float4 v = *reinterpret_cast<const float4*>(Wc + cls * FD + q * 4);
            uint2 p;
            p.x = (unsigned)bf16_rne(v.x) | ((unsigned)bf16_rne(v.y) << 16);
            p.y = (unsigned)bf16_rne(v.z) | ((unsigned)bf16_rne(v.w) << 16);
            *reinterpret_cast<uint2*>(&Wcs[cls * 136 + q * 4]) = p;
        }
#pragma unroll
        for (int mt = 0; mt < 2; ++mt) {
            int row0 = wm * 32 + mt * 16 + kb * 4;
#pragma unroll
            for (int r = 0; r < 4; ++r) {
#pragma unroll
                for (int nt = 0; nt < 4; ++nt) {
                    float v = fmaxf(acc[mt][nt][r] + bz[nt], 0.f);
                    Hs[(row0 + r) * 136 + wn * 64 + nt * 16 + l15] = bf16_rne(v);
                }
            }
        }
        __syncthreads();
        f32x4 c2[3] = {};
#pragma unroll
        for (int kk = 0; kk < 4; ++kk) {
            short8 af = *reinterpret_cast<const short8*>(
                &Hs[(wave * 16 + l15) * 136 + kk * 32 + kb * 8]);
#pragma unroll
            for (int t = 0; t < 3; ++t) {
                short8 bf = *reinterpret_cast<const short8*>(
                    &Wcs[(t * 16 + l15) * 136 + kk * 32 + kb * 8]);
                c2[t] = __builtin_amdgcn_mfma_f32_16x16x32_bf16(af, bf, c2[t], 0, 0, 0);
            }
        }
#pragma unroll
        for (int t = 0; t < 3; ++t) {
            int cls = t * 16 + l15;
            if (cls < NC) {
#pragma unroll
                for (int r = 0; r < 4; ++r) {
                    int gn = nb + wave * 16 + kb * 4 + r;
                    if (gn < NN)
                        outf[(size_t)gn * NC + cls] = c2[t][r] + bc[cls];
                }
            }
        }
    }
}

extern "C" void kernel_launch(void* const* d_in, const int* in_sizes, int n_in,
                              void* d_out, int out_size, void* d_ws, size_t ws_size,
                              hipStream_t stream) {
    const float* x   = (const float*)d_in[0];
    const int*   ei  = (const int*)d_in[1];
    const float* W1l = (const float*)d_in[3];
    const float* b1l = (const float*)d_in[4];
    const float* W1r = (const float*)d_in[5];
    const float* W2l = (const float*)d_in[6];
    const float* b2l = (const float*)d_in[7];
    const float* W2r = (const float*)d_in[8];
    const float* Wc  = (const float*)d_in[9];
    const float* bc  = (const float*)d_in[10];
    float* out = (float*)d_out;

    char* ws = (char*)d_ws;
    int*   deg    = (int*)(ws + WS_DEG);
    int*   off    = (int*)(ws + WS_OFF);
    float* invdeg = (float*)(ws + WS_INVDEG);
    int*   part   = (int*)(ws + WS_PART);
    int*   csr    = (int*)(ws + WS_CSR);
    unsigned short* xb = (unsigned short*)(ws + WS_XB);
    unsigned short* mb = (unsigned short*)(ws + WS_MEAN);
    unsigned short* hb = (unsigned short*)(ws + WS_H);
    unsigned* packed = (unsigned*)(ws + WS_H); // consumed by k_place before hb written

    hipMemsetAsync(deg, 0, NN * sizeof(int), stream);
    k_tobf16<<<2048, 256, 0, stream>>>(x, xb);
    k_ticket<<<2048, 256, 0, stream>>>(ei, deg, packed);
    int G1 = (NN + 1023) / 1024;  // 98
    k_scan1<<<G1, 256, 0, stream>>>(deg, off, part);
    k_scan2<<<1, 256, 0, stream>>>(part, G1);
    k_scan3<<<(NN + 255) / 256, 256, 0, stream>>>(off, part, deg, invdeg);
    k_place<<<2048, 256, 0, stream>>>(packed, ei + NE, off, csr);

    const int GG = (NN + 63) / 64;   // 1563

    // layer 1
    k_agg<<<(NN + 3) / 4, 256, 0, stream>>>(xb, off, csr, invdeg, mb);
    k_gemm<false><<<GG, 256, 0, stream>>>(mb, xb, W1l, W1r, b1l,
                                          nullptr, nullptr, hb, nullptr);
    // layer 2 + fused classifier
    k_agg<<<(NN + 3) / 4, 256, 0, stream>>>(hb, off, csr, invdeg, mb);
    k_gemm<true><<<GG, 256, 0, stream>>>(mb, hb, W2l, W2r, b2l,
                                         Wc, bc, nullptr, out);
}

// Round 6
// 322.666 us; speedup vs baseline: 4.6424x; 1.0686x over previous
//
#include <hip/hip_runtime.h>

#define NN 100000
#define NE 1600000
#define FD 128
#define NC 40

typedef __attribute__((ext_vector_type(8))) short short8;
typedef __attribute__((ext_vector_type(4))) float f32x4;

// ---- workspace layout (bytes) ----
#define WS_DEG      0u
#define WS_OFF      401408u
#define WS_INVDEG   802816u
#define WS_PART     1204224u
#define WS_CSR      1205248u      // E int (6.4 MB)
#define WS_XB       7605248u      // N*128 bf16 (25.6 MB)
#define WS_MEAN     33205248u     // N*128 bf16 (25.6 MB) - mean (both layers)
#define WS_H        58805248u     // N*128 bf16 h1; doubles as u32 ticket[NE] during CSR build

__device__ inline unsigned short bf16_rne(float v) {
    union { float f; unsigned u; } a; a.f = v;
    return (unsigned short)((a.u + 0x7FFFu + ((a.u >> 16) & 1u)) >> 16);
}

__device__ inline void cvt_split(float v, unsigned short& h, unsigned short& l) {
    union { float f; unsigned u; } a; a.f = v;
    unsigned rh = (a.u + 0x7FFFu + ((a.u >> 16) & 1u)) >> 16;
    h = (unsigned short)rh;
    union { unsigned u; float f; } b; b.u = rh << 16;
    float lo = v - b.f;
    union { float f; unsigned u; } c; c.f = lo;
    l = (unsigned short)((c.u + 0x7FFFu + ((c.u >> 16) & 1u)) >> 16);
}

// ---------------- CSR build ----------------
__global__ void k_ticket(const int* __restrict__ ei, int* __restrict__ deg,
                         unsigned* __restrict__ packed) {
    int i = blockIdx.x * blockDim.x + threadIdx.x;
    int stride = gridDim.x * blockDim.x;
    for (int e = i; e < NE; e += stride) {
        int s = ei[e];
        int d = ei[NE + e];
        unsigned r = atomicAdd(&deg[d], 1);
        __builtin_nontemporal_store((unsigned)s | (r << 17), &packed[e]);
    }
}

__global__ void k_scan1(const int* __restrict__ deg, int* __restrict__ off,
                        int* __restrict__ part) {
    __shared__ int s[256];
    int t = threadIdx.x;
    int base = blockIdx.x * 1024 + t * 4;
    int v[4]; int tsum = 0;
#pragma unroll
    for (int j = 0; j < 4; ++j) {
        int idx = base + j;
        v[j] = (idx < NN) ? deg[idx] : 0;
        tsum += v[j];
    }
    s[t] = tsum;
    __syncthreads();
    for (int d = 1; d < 256; d <<= 1) {
        int x = (t >= d) ? s[t - d] : 0;
        __syncthreads();
        s[t] += x;
        __syncthreads();
    }
    int excl = s[t] - tsum;
    if (t == 255) part[blockIdx.x] = s[t];
    int p = excl;
#pragma unroll
    for (int j = 0; j < 4; ++j) {
        int idx = base + j;
        if (idx < NN) off[idx] = p;
        p += v[j];
    }
}

__global__ void k_scan2(int* __restrict__ part, int n) {
    __shared__ int s[256];
    int t = threadIdx.x;
    int v = (t < n) ? part[t] : 0;
    s[t] = v;
    __syncthreads();
    for (int d = 1; d < 256; d <<= 1) {
        int x = (t >= d) ? s[t - d] : 0;
        __syncthreads();
        s[t] += x;
        __syncthreads();
    }
    if (t < n) part[t] = s[t] - v;
}

__global__ void k_scan3(int* __restrict__ off, const int* __restrict__ part,
                        const int* __restrict__ deg, float* __restrict__ invdeg) {
    int i = blockIdx.x * blockDim.x + threadIdx.x;
    if (i == 0) off[NN] = NE;
    if (i < NN) {
        int o = off[i] + part[i >> 10];
        off[i] = o;
        int d = deg[i];
        invdeg[i] = 1.0f / (float)(d > 0 ? d : 1);
    }
}

__global__ void k_place(const unsigned* __restrict__ packed,
                        const int* __restrict__ dst,
                        const int* __restrict__ off, int* __restrict__ csr) {
    int i = blockIdx.x * blockDim.x + threadIdx.x;
    int stride = gridDim.x * blockDim.x;
    for (int e = i; e < NE; e += stride) {
        unsigned p = __builtin_nontemporal_load(&packed[e]);
        int d = dst[e];
        csr[off[d] + (int)(p >> 17)] = (int)(p & 0x1FFFFu);
    }
}

// ---------------- f32 -> bf16 convert ----------------
__global__ void k_tobf16(const float* __restrict__ x, unsigned short* __restrict__ xb) {
    int i = blockIdx.x * blockDim.x + threadIdx.x;
    int stride = gridDim.x * blockDim.x;
    const int total = NN * FD / 8;
    for (int s = i; s < total; s += stride) {
        float4 a = *reinterpret_cast<const float4*>(x + (size_t)s * 8);
        float4 b = *reinterpret_cast<const float4*>(x + (size_t)s * 8 + 4);
        short8 o;
        o[0] = (short)bf16_rne(a.x); o[1] = (short)bf16_rne(a.y);
        o[2] = (short)bf16_rne(a.z); o[3] = (short)bf16_rne(a.w);
        o[4] = (short)bf16_rne(b.x); o[5] = (short)bf16_rne(b.y);
        o[6] = (short)bf16_rne(b.z); o[7] = (short)bf16_rne(b.w);
        *reinterpret_cast<short8*>(xb + (size_t)s * 8) = o;
    }
}

// ---------------- mean aggregation: wave/node, 4 edges x 16B per instr ----
__device__ inline void acc8(float* a, uint4 v) {
    a[0] += __uint_as_float(v.x << 16);
    a[1] += __uint_as_float(v.x & 0xFFFF0000u);
    a[2] += __uint_as_float(v.y << 16);
    a[3] += __uint_as_float(v.y & 0xFFFF0000u);
    a[4] += __uint_as_float(v.z << 16);
    a[5] += __uint_as_float(v.z & 0xFFFF0000u);
    a[6] += __uint_as_float(v.w << 16);
    a[7] += __uint_as_float(v.w & 0xFFFF0000u);
}

__global__ __launch_bounds__(256) void k_agg(const unsigned short* __restrict__ Xb,
                                             const int* __restrict__ off,
                                             const int* __restrict__ csr,
                                             const float* __restrict__ invdeg,
                                             unsigned short* __restrict__ Mb) {
    int wid = (blockIdx.x * 256 + threadIdx.x) >> 6;
    int lane = threadIdx.x & 63;
    if (wid >= NN) return;
    const int g  = lane >> 4;     // edge slot within quad (0..3)
    const int fc = lane & 15;     // feature chunk (8 bf16 = 16B)
    const unsigned short* Xl = Xb + fc * 8;
    int s0 = off[wid], s1 = off[wid + 1];
    float a[8] = {};
    int e = s0;
    // main: 8 edges per iteration (2 quads in flight, 2KB/wave)
    for (; e + 7 < s1; e += 8) {
        int r0 = csr[e + g];
        int r1 = csr[e + 4 + g];
        uint4 v0 = *reinterpret_cast<const uint4*>(Xl + ((size_t)r0 << 7));
        uint4 v1 = *reinterpret_cast<const uint4*>(Xl + ((size_t)r1 << 7));
        acc8(a, v0);
        acc8(a, v1);
    }
    // tail: masked quads
    for (; e < s1; e += 4) {
        int cnt = s1 - e;
        int r = csr[e + (g < cnt ? g : 0)];
        uint4 v = *reinterpret_cast<const uint4*>(Xl + ((size_t)r << 7));
        if (g < cnt) acc8(a, v);
    }
    // reduce across the 4 edge-slot groups
#pragma unroll
    for (int j = 0; j < 8; ++j) {
        a[j] += __shfl_xor(a[j], 32);
        a[j] += __shfl_xor(a[j], 16);
    }
    if (g == 0) {
        float w = invdeg[wid];
        uint4 o;
        o.x = (unsigned)bf16_rne(a[0] * w) | ((unsigned)bf16_rne(a[1] * w) << 16);
        o.y = (unsigned)bf16_rne(a[2] * w) | ((unsigned)bf16_rne(a[3] * w) << 16);
        o.z = (unsigned)bf16_rne(a[4] * w) | ((unsigned)bf16_rne(a[5] * w) << 16);
        o.w = (unsigned)bf16_rne(a[6] * w) | ((unsigned)bf16_rne(a[7] * w) << 16);
        *reinterpret_cast<uint4*>(Mb + (size_t)wid * FD + fc * 8) = o;
    }
}

// ---------------- dual GEMM via MFMA (+fused classifier) ----------------
template <bool FUSE>
__global__ __launch_bounds__(256, 3) void k_gemm(
        const unsigned short* __restrict__ M,
        const unsigned short* __restrict__ X,
        const float* __restrict__ Wl,
        const float* __restrict__ Wr,
        const float* __restrict__ bias,
        const float* __restrict__ Wc,
        const float* __restrict__ bc,
        unsigned short* outb, float* outf) {
    __shared__ __align__(16) unsigned short pool[FUSE ? 21504 : 12800];
    unsigned short* Ah = pool;            // [64][40]
    unsigned short* Bh = pool + 2560;     // [128][40]
    unsigned short* Bl = pool + 7680;     // [128][40]

    const int tid = threadIdx.x;
    const int wave = tid >> 6;
    const int lane = tid & 63;
    const int wm = wave & 1;
    const int wn = wave >> 1;
    const int nb = blockIdx.x * 64;
    const int l15 = lane & 15;
    const int kb = lane >> 4;

    f32x4 acc[2][4] = {};

    for (int c = 0; c < 8; ++c) {
        const unsigned short* A = (c < 4) ? M : X;
        const float* W = (c < 4) ? Wl : Wr;
        const int kc = (c & 3) * 32;
        __syncthreads();
        {
            int row = tid >> 2, seg = tid & 3;
            int gn = nb + row;
            short8 v = {};
            if (gn < NN)
                v = *reinterpret_cast<const short8*>(A + (size_t)gn * FD + kc + seg * 8);
            *reinterpret_cast<short8*>(&Ah[row * 40 + seg * 8]) = v;
        }
#pragma unroll
        for (int r = 0; r < 4; ++r) {
            int slot = tid + 256 * r;
            int o = slot >> 3, q = slot & 7;
            float4 v = *reinterpret_cast<const float4*>(W + o * FD + kc + q * 4);
            unsigned short h0, h1, h2, h3, l0, l1, l2, l3;
            cvt_split(v.x, h0, l0); cvt_split(v.y, h1, l1);
            cvt_split(v.z, h2, l2); cvt_split(v.w, h3, l3);
            uint2 ph, pl;
            ph.x = (unsigned)h0 | ((unsigned)h1 << 16);
            ph.y = (unsigned)h2 | ((unsigned)h3 << 16);
            pl.x = (unsigned)l0 | ((unsigned)l1 << 16);
            pl.y = (unsigned)l2 | ((unsigned)l3 << 16);
            *reinterpret_cast<uint2*>(&Bh[o * 40 + q * 4]) = ph;
            *reinterpret_cast<uint2*>(&Bl[o * 40 + q * 4]) = pl;
        }
        __syncthreads();
        short8 a[2], b_h[4], b_l[4];
#pragma unroll
        for (int mt = 0; mt < 2; ++mt) {
            int row = wm * 32 + mt * 16 + l15;
            a[mt] = *reinterpret_cast<const short8*>(&Ah[row * 40 + kb * 8]);
        }
#pragma unroll
        for (int nt = 0; nt < 4; ++nt) {
            int o = wn * 64 + nt * 16 + l15;
            b_h[nt] = *reinterpret_cast<const short8*>(&Bh[o * 40 + kb * 8]);
            b_l[nt] = *reinterpret_cast<const short8*>(&Bl[o * 40 + kb * 8]);
        }
#pragma unroll
        for (int mt = 0; mt < 2; ++mt)
#pragma unroll
            for (int nt = 0; nt < 4; ++nt) {
                acc[mt][nt] = __builtin_amdgcn_mfma_f32_16x16x32_bf16(a[mt], b_h[nt], acc[mt][nt], 0, 0, 0);
                acc[mt][nt] = __builtin_amdgcn_mfma_f32_16x16x32_bf16(a[mt], b_l[nt], acc[mt][nt], 0, 0, 0);
            }
    }

    float bz[4];
#pragma unroll
    for (int nt = 0; nt < 4; ++nt) bz[nt] = bias[wn * 64 + nt * 16 + l15];

    if (!FUSE) {
#pragma unroll
        for (int mt = 0; mt < 2; ++mt) {
            int gn0 = nb + wm * 32 + mt * 16 + kb * 4;
#pragma unroll
            for (int r = 0; r < 4; ++r) {
                int gn = gn0 + r;
                if (gn < NN) {
#pragma unroll
                    for (int nt = 0; nt < 4; ++nt) {
                        float v = fmaxf(acc[mt][nt][r] + bz[nt], 0.f);
                        outb[(size_t)gn * FD + wn * 64 + nt * 16 + l15] = bf16_rne(v);
                    }
                }
            }
        }
    } else {
        unsigned short* Hs  = pool + 12800;   // [64][136]
        unsigned short* Wcs = pool;           // [48][136]
        __syncthreads();
#pragma unroll
        for (int r = 0; r < 5; ++r) {
            int slot = tid + 256 * r;
            int cls = slot >> 5, q = slot & 31;
            float4 v = *reinterpret_cast<const float4*>(Wc + cls * FD + q * 4);
            uint2 p;
            p.x = (unsigned)bf16_rne(v.x) | ((unsigned)bf16_rne(v.y) << 16);
            p.y = (unsigned)bf16_rne(v.z) | ((unsigned)bf16_rne(v.w) << 16);
            *reinterpret_cast<uint2*>(&Wcs[cls * 136 + q * 4]) = p;
        }
#pragma unroll
        for (int mt = 0; mt < 2; ++mt) {
            int row0 = wm * 32 + mt * 16 + kb * 4;
#pragma unroll
            for (int r = 0; r < 4; ++r) {
#pragma unroll
                for (int nt = 0; nt < 4; ++nt) {
                    float v = fmaxf(acc[mt][nt][r] + bz[nt], 0.f);
                    Hs[(row0 + r) * 136 + wn * 64 + nt * 16 + l15] = bf16_rne(v);
                }
            }
        }
        __syncthreads();
        f32x4 c2[3] = {};
#pragma unroll
        for (int kk = 0; kk < 4; ++kk) {
            short8 af = *reinterpret_cast<const short8*>(
                &Hs[(wave * 16 + l15) * 136 + kk * 32 + kb * 8]);
#pragma unroll
            for (int t = 0; t < 3; ++t) {
                short8 bf = *reinterpret_cast<const short8*>(
                    &Wcs[(t * 16 + l15) * 136 + kk * 32 + kb * 8]);
                c2[t] = __builtin_amdgcn_mfma_f32_16x16x32_bf16(af, bf, c2[t], 0, 0, 0);
            }
        }
#pragma unroll
        for (int t = 0; t < 3; ++t) {
            int cls = t * 16 + l15;
            if (cls < NC) {
#pragma unroll
                for (int r = 0; r < 4; ++r) {
                    int gn = nb + wave * 16 + kb * 4 + r;
                    if (gn < NN)
                        outf[(size_t)gn * NC + cls] = c2[t][r] + bc[cls];
                }
            }
        }
    }
}

extern "C" void kernel_launch(void* const* d_in, const int* in_sizes, int n_in,
                              void* d_out, int out_size, void* d_ws, size_t ws_size,
                              hipStream_t stream) {
    const float* x   = (const float*)d_in[0];
    const int*   ei  = (const int*)d_in[1];
    const float* W1l = (const float*)d_in[3];
    const float* b1l = (const float*)d_in[4];
    const float* W1r = (const float*)d_in[5];
    const float* W2l = (const float*)d_in[6];
    const float* b2l = (const float*)d_in[7];
    const float* W2r = (const float*)d_in[8];
    const float* Wc  = (const float*)d_in[9];
    const float* bc  = (const float*)d_in[10];
    float* out = (float*)d_out;

    char* ws = (char*)d_ws;
    int*   deg    = (int*)(ws + WS_DEG);
    int*   off    = (int*)(ws + WS_OFF);
    float* invdeg = (float*)(ws + WS_INVDEG);
    int*   part   = (int*)(ws + WS_PART);
    int*   csr    = (int*)(ws + WS_CSR);
    unsigned short* xb = (unsigned short*)(ws + WS_XB);
    unsigned short* mb = (unsigned short*)(ws + WS_MEAN);
    unsigned short* hb = (unsigned short*)(ws + WS_H);
    unsigned* packed = (unsigned*)(ws + WS_H); // consumed by k_place before hb written

    hipMemsetAsync(deg, 0, NN * sizeof(int), stream);
    k_tobf16<<<2048, 256, 0, stream>>>(x, xb);
    k_ticket<<<2048, 256, 0, stream>>>(ei, deg, packed);
    int G1 = (NN + 1023) / 1024;  // 98
    k_scan1<<<G1, 256, 0, stream>>>(deg, off, part);
    k_scan2<<<1, 256, 0, stream>>>(part, G1);
    k_scan3<<<(NN + 255) / 256, 256, 0, stream>>>(off, part, deg, invdeg);
    k_place<<<2048, 256, 0, stream>>>(packed, ei + NE, off, csr);

    const int GG = (NN + 63) / 64;   // 1563

    // layer 1
    k_agg<<<(NN + 3) / 4, 256, 0, stream>>>(xb, off, csr, invdeg, mb);
    k_gemm<false><<<GG, 256, 0, stream>>>(mb, xb, W1l, W1r, b1l,
                                          nullptr, nullptr, hb, nullptr);
    // layer 2 + fused classifier
    k_agg<<<(NN + 3) / 4, 256, 0, stream>>>(hb, off, csr, invdeg, mb);
    k_gemm<true><<<GG, 256, 0, stream>>>(mb, hb, W2l, W2r, b2l,
                                         Wc, bc, nullptr, out);
}

// Round 7
// 309.262 us; speedup vs baseline: 4.8436x; 1.0433x over previous
//
#include <hip/hip_runtime.h>

#define NN 100000
#define NE 1600000
#define FD 128
#define NC 40

typedef __attribute__((ext_vector_type(8))) short short8;
typedef __attribute__((ext_vector_type(4))) float f32x4;

// ---- workspace layout (bytes) ----
#define WS_DEGP     0u            // NN*16 int, one counter per 64B line (6.4 MB)
#define WS_OFF      6553600u      // (NN+1) int
#define WS_INVDEG   6953728u      // NN float
#define WS_PART     7353856u      // 256 int
#define WS_WB       7354880u      // split weights: 4 mats x (hi16384+lo16384) bf16 + Wc bf16
#define WS_CSR      7627264u      // NE int (6.4 MB)
#define WS_XB       14027392u     // NN*FD bf16 (25.6 MB)
#define WS_MB       39627520u     // NN*FD bf16 mean
#define WS_HB       65227648u     // NN*FD bf16 h1; aliases u32 ticket[NE] during build

#define CONVB 512
#define TICKB 2048

__device__ inline unsigned short bf16_rne(float v) {
    union { float f; unsigned u; } a; a.f = v;
    return (unsigned short)((a.u + 0x7FFFu + ((a.u >> 16) & 1u)) >> 16);
}

__device__ inline void cvt_split(float v, unsigned short& h, unsigned short& l) {
    union { float f; unsigned u; } a; a.f = v;
    unsigned rh = (a.u + 0x7FFFu + ((a.u >> 16) & 1u)) >> 16;
    h = (unsigned short)rh;
    union { unsigned u; float f; } b; b.u = rh << 16;
    float lo = v - b.f;
    union { float f; unsigned u; } c; c.f = lo;
    l = (unsigned short)((c.u + 0x7FFFu + ((c.u >> 16) & 1u)) >> 16);
}

// ---------------- fused: bf16 convert (blocks 0..CONVB) + rank ticket ------
__global__ __launch_bounds__(256) void k_ticket_conv(
        const int* __restrict__ ei, int* __restrict__ degp,
        unsigned* __restrict__ packed,
        const float* __restrict__ x, unsigned short* __restrict__ xb) {
    if (blockIdx.x < CONVB) {
        int i = blockIdx.x * 256 + threadIdx.x;
        const int total = NN * FD / 8;
        for (int s = i; s < total; s += CONVB * 256) {
            float4 a = *reinterpret_cast<const float4*>(x + (size_t)s * 8);
            float4 b = *reinterpret_cast<const float4*>(x + (size_t)s * 8 + 4);
            short8 o;
            o[0] = (short)bf16_rne(a.x); o[1] = (short)bf16_rne(a.y);
            o[2] = (short)bf16_rne(a.z); o[3] = (short)bf16_rne(a.w);
            o[4] = (short)bf16_rne(b.x); o[5] = (short)bf16_rne(b.y);
            o[6] = (short)bf16_rne(b.z); o[7] = (short)bf16_rne(b.w);
            *reinterpret_cast<short8*>(xb + (size_t)s * 8) = o;
        }
    } else {
        int i = (blockIdx.x - CONVB) * 256 + threadIdx.x;
        for (int e = i; e < NE; e += TICKB * 256) {
            int s = ei[e];
            int d = ei[NE + e];
            unsigned r = atomicAdd((unsigned*)&degp[(size_t)d << 4], 1u);
            __builtin_nontemporal_store((unsigned)s | (r << 17), &packed[e]);
        }
    }
}

// ---------------- scans (read padded counters) ----------------
__global__ void k_scan1(const int* __restrict__ degp, int* __restrict__ off,
                        int* __restrict__ part) {
    __shared__ int s[256];
    int t = threadIdx.x;
    int base = blockIdx.x * 1024 + t * 4;
    int v[4]; int tsum = 0;
#pragma unroll
    for (int j = 0; j < 4; ++j) {
        int idx = base + j;
        v[j] = (idx < NN) ? degp[(size_t)idx << 4] : 0;
        tsum += v[j];
    }
    s[t] = tsum;
    __syncthreads();
    for (int d = 1; d < 256; d <<= 1) {
        int x = (t >= d) ? s[t - d] : 0;
        __syncthreads();
        s[t] += x;
        __syncthreads();
    }
    int excl = s[t] - tsum;
    if (t == 255) part[blockIdx.x] = s[t];
    int p = excl;
#pragma unroll
    for (int j = 0; j < 4; ++j) {
        int idx = base + j;
        if (idx < NN) off[idx] = p;
        p += v[j];
    }
}

__global__ void k_scan2(int* __restrict__ part, int n) {
    __shared__ int s[256];
    int t = threadIdx.x;
    int v = (t < n) ? part[t] : 0;
    s[t] = v;
    __syncthreads();
    for (int d = 1; d < 256; d <<= 1) {
        int x = (t >= d) ? s[t - d] : 0;
        __syncthreads();
        s[t] += x;
        __syncthreads();
    }
    if (t < n) part[t] = s[t] - v;
}

__global__ void k_scan3(int* __restrict__ off, const int* __restrict__ part,
                        const int* __restrict__ degp, float* __restrict__ invdeg) {
    int i = blockIdx.x * blockDim.x + threadIdx.x;
    if (i == 0) off[NN] = NE;
    if (i < NN) {
        int o = off[i] + part[i >> 10];
        off[i] = o;
        int d = degp[(size_t)i << 4];
        invdeg[i] = 1.0f / (float)(d > 0 ? d : 1);
    }
}

__global__ void k_place(const unsigned* __restrict__ packed,
                        const int* __restrict__ dst,
                        const int* __restrict__ off, int* __restrict__ csr) {
    int i = blockIdx.x * blockDim.x + threadIdx.x;
    int stride = gridDim.x * blockDim.x;
    for (int e = i; e < NE; e += stride) {
        unsigned p = __builtin_nontemporal_load(&packed[e]);
        int d = dst[e];
        csr[off[d] + (int)(p >> 17)] = (int)(p & 0x1FFFFu);
    }
}

// ---------------- one-time weight split: f32 -> (hi,lo) bf16 ----------------
// wb halfword layout: mat m in {W1l,W1r,W2l,W2r}: hi at m*32768+e, lo at +16384.
// Wc bf16 at 131072 + j (40*128).
__global__ void k_prepw(const float* __restrict__ W1l, const float* __restrict__ W1r,
                        const float* __restrict__ W2l, const float* __restrict__ W2r,
                        const float* __restrict__ Wc, unsigned short* __restrict__ wb) {
    int i = blockIdx.x * 256 + threadIdx.x;
    if (i < 65536) {
        int m = i >> 14, e = i & 16383;
        const float* W = (m == 0) ? W1l : (m == 1) ? W1r : (m == 2) ? W2l : W2r;
        unsigned short h, l;
        cvt_split(W[e], h, l);
        wb[m * 32768 + e] = h;
        wb[m * 32768 + 16384 + e] = l;
    } else if (i < 65536 + NC * FD) {
        int j = i - 65536;
        wb[131072 + j] = bf16_rne(Wc[j]);
    }
}

// ---------------- mean aggregation: wave/node, 4 edges x 16B per instr ----
__device__ inline void acc8(float* a, uint4 v) {
    a[0] += __uint_as_float(v.x << 16);
    a[1] += __uint_as_float(v.x & 0xFFFF0000u);
    a[2] += __uint_as_float(v.y << 16);
    a[3] += __uint_as_float(v.y & 0xFFFF0000u);
    a[4] += __uint_as_float(v.z << 16);
    a[5] += __uint_as_float(v.z & 0xFFFF0000u);
    a[6] += __uint_as_float(v.w << 16);
    a[7] += __uint_as_float(v.w & 0xFFFF0000u);
}

__global__ __launch_bounds__(256) void k_agg(const unsigned short* __restrict__ Xb,
                                             const int* __restrict__ off,
                                             const int* __restrict__ csr,
                                             const float* __restrict__ invdeg,
                                             unsigned short* __restrict__ Mb) {
    int wid = (blockIdx.x * 256 + threadIdx.x) >> 6;
    int lane = threadIdx.x & 63;
    if (wid >= NN) return;
    const int g  = lane >> 4;
    const int fc = lane & 15;
    const unsigned short* Xl = Xb + fc * 8;
    int s0 = off[wid], s1 = off[wid + 1];
    float a[8] = {};
    int e = s0;
    for (; e + 7 < s1; e += 8) {
        int r0 = csr[e + g];
        int r1 = csr[e + 4 + g];
        uint4 v0 = *reinterpret_cast<const uint4*>(Xl + ((size_t)r0 << 7));
        uint4 v1 = *reinterpret_cast<const uint4*>(Xl + ((size_t)r1 << 7));
        acc8(a, v0);
        acc8(a, v1);
    }
    for (; e < s1; e += 4) {
        int cnt = s1 - e;
        int r = csr[e + (g < cnt ? g : 0)];
        uint4 v = *reinterpret_cast<const uint4*>(Xl + ((size_t)r << 7));
        if (g < cnt) acc8(a, v);
    }
#pragma unroll
    for (int j = 0; j < 8; ++j) {
        a[j] += __shfl_xor(a[j], 32);
        a[j] += __shfl_xor(a[j], 16);
    }
    if (g == 0) {
        float w = invdeg[wid];
        uint4 o;
        o.x = (unsigned)bf16_rne(a[0] * w) | ((unsigned)bf16_rne(a[1] * w) << 16);
        o.y = (unsigned)bf16_rne(a[2] * w) | ((unsigned)bf16_rne(a[3] * w) << 16);
        o.z = (unsigned)bf16_rne(a[4] * w) | ((unsigned)bf16_rne(a[5] * w) << 16);
        o.w = (unsigned)bf16_rne(a[6] * w) | ((unsigned)bf16_rne(a[7] * w) << 16);
        *reinterpret_cast<uint4*>(Mb + (size_t)wid * FD + fc * 8) = o;
    }
}

// ---------------- dual GEMM via MFMA (+fused classifier) ----------------
// Wl/Wr point at a split-weight block: hi bf16 [128][128] at +0, lo at +16384.
template <bool FUSE>
__global__ __launch_bounds__(256, 3) void k_gemm(
        const unsigned short* __restrict__ M,
        const unsigned short* __restrict__ X,
        const unsigned short* __restrict__ Wl,
        const unsigned short* __restrict__ Wr,
        const float* __restrict__ bias,
        const unsigned short* __restrict__ Wcb,
        const float* __restrict__ bc,
        unsigned short* outb, float* outf) {
    __shared__ __align__(16) unsigned short pool[FUSE ? 21504 : 12800];
    unsigned short* Ah = pool;            // [64][40]
    unsigned short* Bh = pool + 2560;     // [128][40]
    unsigned short* Bl = pool + 7680;     // [128][40]

    const int tid = threadIdx.x;
    const int wave = tid >> 6;
    const int lane = tid & 63;
    const int wm = wave & 1;
    const int wn = wave >> 1;
    const int nb = blockIdx.x * 64;
    const int l15 = lane & 15;
    const int kb = lane >> 4;

    f32x4 acc[2][4] = {};

    for (int c = 0; c < 8; ++c) {
        const unsigned short* A = (c < 4) ? M : X;
        const unsigned short* W = (c < 4) ? Wl : Wr;
        const int kc = (c & 3) * 32;
        __syncthreads();
        {
            int row = tid >> 2, seg = tid & 3;
            int gn = nb + row;
            short8 v = {};
            if (gn < NN)
                v = *reinterpret_cast<const short8*>(A + (size_t)gn * FD + kc + seg * 8);
            *reinterpret_cast<short8*>(&Ah[row * 40 + seg * 8]) = v;
        }
#pragma unroll
        for (int r = 0; r < 2; ++r) {
            int slot = tid + 256 * r;     // < 512: 128 rows x 4 segs
            int o = slot >> 2, seg = slot & 3;
            short8 vh = *reinterpret_cast<const short8*>(W + o * FD + kc + seg * 8);
            short8 vl = *reinterpret_cast<const short8*>(W + 16384 + o * FD + kc + seg * 8);
            *reinterpret_cast<short8*>(&Bh[o * 40 + seg * 8]) = vh;
            *reinterpret_cast<short8*>(&Bl[o * 40 + seg * 8]) = vl;
        }
        __syncthreads();
        short8 a[2], b_h[4], b_l[4];
#pragma unroll
        for (int mt = 0; mt < 2; ++mt) {
            int row = wm * 32 + mt * 16 + l15;
            a[mt] = *reinterpret_cast<const short8*>(&Ah[row * 40 + kb * 8]);
        }
#pragma unroll
        for (int nt = 0; nt < 4; ++nt) {
            int o = wn * 64 + nt * 16 + l15;
            b_h[nt] = *reinterpret_cast<const short8*>(&Bh[o * 40 + kb * 8]);
            b_l[nt] = *reinterpret_cast<const short8*>(&Bl[o * 40 + kb * 8]);
        }
#pragma unroll
        for (int mt = 0; mt < 2; ++mt)
#pragma unroll
            for (int nt = 0; nt < 4; ++nt) {
                acc[mt][nt] = __builtin_amdgcn_mfma_f32_16x16x32_bf16(a[mt], b_h[nt], acc[mt][nt], 0, 0, 0);
                acc[mt][nt] = __builtin_amdgcn_mfma_f32_16x16x32_bf16(a[mt], b_l[nt], acc[mt][nt], 0, 0, 0);
            }
    }

    float bz[4];
#pragma unroll
    for (int nt = 0; nt < 4; ++nt) bz[nt] = bias[wn * 64 + nt * 16 + l15];

    if (!FUSE) {
#pragma unroll
        for (int mt = 0; mt < 2; ++mt) {
            int gn0 = nb + wm * 32 + mt * 16 + kb * 4;
#pragma unroll
            for (int r = 0; r < 4; ++r) {
                int gn = gn0 + r;
                if (gn < NN) {
#pragma unroll
                    for (int nt = 0; nt < 4; ++nt) {
                        float v = fmaxf(acc[mt][nt][r] + bz[nt], 0.f);
                        outb[(size_t)gn * FD + wn * 64 + nt * 16 + l15] = bf16_rne(v);
                    }
                }
            }
        }
    } else {
        unsigned short* Hs  = pool + 12800;   // [64][136]
        unsigned short* Wcs = pool;           // [40][136] (reuses staging)
        __syncthreads();
#pragma unroll
        for (int r = 0; r < 3; ++r) {
            int slot = tid + 256 * r;         // 640 slots: 40 rows x 16 segs
            if (slot < 640) {
                int row = slot >> 4, seg = slot & 15;
                *reinterpret_cast<short8*>(&Wcs[row * 136 + seg * 8]) =
                    *reinterpret_cast<const short8*>(Wcb + row * FD + seg * 8);
            }
        }
#pragma unroll
        for (int mt = 0; mt < 2; ++mt) {
            int row0 = wm * 32 + mt * 16 + kb * 4;
#pragma unroll
            for (int r = 0; r < 4; ++r) {
#pragma unroll
                for (int nt = 0; nt < 4; ++nt) {
                    float v = fmaxf(acc[mt][nt][r] + bz[nt], 0.f);
                    Hs[(row0 + r) * 136 + wn * 64 + nt * 16 + l15] = bf16_rne(v);
                }
            }
        }
        __syncthreads();
        f32x4 c2[3] = {};
#pragma unroll
        for (int kk = 0; kk < 4; ++kk) {
            short8 af = *reinterpret_cast<const short8*>(
                &Hs[(wave * 16 + l15) * 136 + kk * 32 + kb * 8]);
#pragma unroll
            for (int t = 0; t < 3; ++t) {
                short8 bf = *reinterpret_cast<const short8*>(
                    &Wcs[(t * 16 + l15) * 136 + kk * 32 + kb * 8]);
                c2[t] = __builtin_amdgcn_mfma_f32_16x16x32_bf16(af, bf, c2[t], 0, 0, 0);
            }
        }
#pragma unroll
        for (int t = 0; t < 3; ++t) {
            int cls = t * 16 + l15;
            if (cls < NC) {
#pragma unroll
                for (int r = 0; r < 4; ++r) {
                    int gn = nb + wave * 16 + kb * 4 + r;
                    if (gn < NN)
                        outf[(size_t)gn * NC + cls] = c2[t][r] + bc[cls];
                }
            }
        }
    }
}

extern "C" void kernel_launch(void* const* d_in, const int* in_sizes, int n_in,
                              void* d_out, int out_size, void* d_ws, size_t ws_size,
                              hipStream_t stream) {
    const float* x   = (const float*)d_in[0];
    const int*   ei  = (const int*)d_in[1];
    const float* W1l = (const float*)d_in[3];
    const float* b1l = (const float*)d_in[4];
    const float* W1r = (const float*)d_in[5];
    const float* W2l = (const float*)d_in[6];
    const float* b2l = (const float*)d_in[7];
    const float* W2r = (const float*)d_in[8];
    const float* Wc  = (const float*)d_in[9];
    const float* bc  = (const float*)d_in[10];
    float* out = (float*)d_out;

    char* ws = (char*)d_ws;
    int*   degp   = (int*)(ws + WS_DEGP);
    int*   off    = (int*)(ws + WS_OFF);
    float* invdeg = (float*)(ws + WS_INVDEG);
    int*   part   = (int*)(ws + WS_PART);
    unsigned short* wb = (unsigned short*)(ws + WS_WB);
    int*   csr    = (int*)(ws + WS_CSR);
    unsigned short* xb = (unsigned short*)(ws + WS_XB);
    unsigned short* mb = (unsigned short*)(ws + WS_MB);
    unsigned short* hb = (unsigned short*)(ws + WS_HB);
    unsigned* packed = (unsigned*)(ws + WS_HB); // consumed by k_place before hb written

    hipMemsetAsync(degp, 0, (size_t)NN * 16 * sizeof(int), stream);
    k_prepw<<<276, 256, 0, stream>>>(W1l, W1r, W2l, W2r, Wc, wb);
    k_ticket_conv<<<CONVB + TICKB, 256, 0, stream>>>(ei, degp, packed, x, xb);
    int G1 = (NN + 1023) / 1024;  // 98
    k_scan1<<<G1, 256, 0, stream>>>(degp, off, part);
    k_scan2<<<1, 256, 0, stream>>>(part, G1);
    k_scan3<<<(NN + 255) / 256, 256, 0, stream>>>(off, part, degp, invdeg);
    k_place<<<2048, 256, 0, stream>>>(packed, ei + NE, off, csr);

    const int GG = (NN + 63) / 64;   // 1563

    // layer 1
    k_agg<<<(NN + 3) / 4, 256, 0, stream>>>(xb, off, csr, invdeg, mb);
    k_gemm<false><<<GG, 256, 0, stream>>>(mb, xb, wb, wb + 32768, b1l,
                                          nullptr, nullptr, hb, nullptr);
    // layer 2 + fused classifier
    k_agg<<<(NN + 3) / 4, 256, 0, stream>>>(hb, off, csr, invdeg, mb);
    k_gemm<true><<<GG, 256, 0, stream>>>(mb, hb, wb + 65536, wb + 98304, b2l,
                                         wb + 131072, bc, nullptr, out);
}

// Round 8
// 243.811 us; speedup vs baseline: 6.1438x; 1.2684x over previous
//
#include <hip/hip_runtime.h>

#define NN 100000
#define NE 1600000
#define FD 128
#define NC 40
#define NBK 782            // ceil(NN/128) buckets of 128 nodes
#define HISTB 256          // histogram / scatter blocks
#define CONVB 512          // bf16-convert blocks fused into P1
#define CHUNK (NE / HISTB) // 6250 edges per block (exact)

typedef __attribute__((ext_vector_type(8))) short short8;
typedef __attribute__((ext_vector_type(4))) float f32x4;

// ---- workspace layout (bytes) ----
#define WS_OFF      0u          // (NN+1) int
#define WS_INVDEG   400384u     // NN float
#define WS_CNT      800512u     // [HISTB][NBK] int (800768 B)
#define WS_BTOT     1601280u    // NBK int
#define WS_BKO      1604480u    // (NBK+1) int
#define WS_WB       1607680u    // split weights + Wc bf16 (272384 B)
#define WS_CSR      1880576u    // NE int (6.4 MB)
#define WS_XB       8280576u    // NN*FD bf16 (25.6 MB)
#define WS_MB       33880576u   // NN*FD bf16 mean
#define WS_HB       59480576u   // NN*FD bf16 h1; aliases u32 bval[NE] during build

__device__ inline unsigned short bf16_rne(float v) {
    union { float f; unsigned u; } a; a.f = v;
    return (unsigned short)((a.u + 0x7FFFu + ((a.u >> 16) & 1u)) >> 16);
}

__device__ inline void cvt_split(float v, unsigned short& h, unsigned short& l) {
    union { float f; unsigned u; } a; a.f = v;
    unsigned rh = (a.u + 0x7FFFu + ((a.u >> 16) & 1u)) >> 16;
    h = (unsigned short)rh;
    union { unsigned u; float f; } b; b.u = rh << 16;
    float lo = v - b.f;
    union { float f; unsigned u; } c; c.f = lo;
    l = (unsigned short)((c.u + 0x7FFFu + ((c.u >> 16) & 1u)) >> 16);
}

// ---------------- P1: fused bf16 convert + bucket histogram ----------------
__global__ __launch_bounds__(256) void k_p1(
        const int* __restrict__ ei, int* __restrict__ cnt,
        const float* __restrict__ x, unsigned short* __restrict__ xb) {
    if (blockIdx.x < CONVB) {
        int i = blockIdx.x * 256 + threadIdx.x;
        const int total = NN * FD / 8;
        for (int s = i; s < total; s += CONVB * 256) {
            float4 a = *reinterpret_cast<const float4*>(x + (size_t)s * 8);
            float4 b = *reinterpret_cast<const float4*>(x + (size_t)s * 8 + 4);
            short8 o;
            o[0] = (short)bf16_rne(a.x); o[1] = (short)bf16_rne(a.y);
            o[2] = (short)bf16_rne(a.z); o[3] = (short)bf16_rne(a.w);
            o[4] = (short)bf16_rne(b.x); o[5] = (short)bf16_rne(b.y);
            o[6] = (short)bf16_rne(b.z); o[7] = (short)bf16_rne(b.w);
            *reinterpret_cast<short8*>(xb + (size_t)s * 8) = o;
        }
    } else {
        __shared__ int hist[NBK];
        const int* dst = ei + NE;
        int blk = blockIdx.x - CONVB;
        for (int j = threadIdx.x; j < NBK; j += 256) hist[j] = 0;
        __syncthreads();
        int base = blk * CHUNK;
        for (int i = threadIdx.x; i < CHUNK; i += 256)
            atomicAdd(&hist[dst[base + i] >> 7], 1);
        __syncthreads();
        for (int j = threadIdx.x; j < NBK; j += 256)
            cnt[blk * NBK + j] = hist[j];
    }
}

// ---------------- P2a: per-bucket exclusive scan over blocks ----------------
__global__ __launch_bounds__(256) void k_p2a(int* __restrict__ cnt,
                                             int* __restrict__ btot) {
    __shared__ int s[256];
    int b = blockIdx.x, t = threadIdx.x;
    int v = cnt[t * NBK + b];
    s[t] = v;
    __syncthreads();
    for (int d = 1; d < 256; d <<= 1) {
        int x = (t >= d) ? s[t - d] : 0;
        __syncthreads();
        s[t] += x;
        __syncthreads();
    }
    cnt[t * NBK + b] = s[t] - v;       // exclusive prefix (lpre)
    if (t == 255) btot[b] = s[255];
}

// ---------------- P2b: scan bucket totals -> bko ----------------
__global__ __launch_bounds__(256) void k_p2b(const int* __restrict__ btot,
                                             int* __restrict__ bko) {
    __shared__ int s[256];
    int t = threadIdx.x;
    int base = t * 4;
    int v[4]; int tsum = 0;
#pragma unroll
    for (int j = 0; j < 4; ++j) {
        int idx = base + j;
        v[j] = (idx < NBK) ? btot[idx] : 0;
        tsum += v[j];
    }
    s[t] = tsum;
    __syncthreads();
    for (int d = 1; d < 256; d <<= 1) {
        int x = (t >= d) ? s[t - d] : 0;
        __syncthreads();
        s[t] += x;
        __syncthreads();
    }
    int p = s[t] - tsum;
#pragma unroll
    for (int j = 0; j < 4; ++j) {
        int idx = base + j;
        if (idx <= NBK) bko[idx] = p;
        p += v[j];
    }
}

// ---------------- P3: scatter edges into bucket-major bval ----------------
__global__ __launch_bounds__(256) void k_p3(const int* __restrict__ ei,
                                            const int* __restrict__ cnt,
                                            const int* __restrict__ bko,
                                            unsigned* __restrict__ bval) {
    __shared__ int cur[NBK];
    int blk = blockIdx.x;
    for (int j = threadIdx.x; j < NBK; j += 256)
        cur[j] = bko[j] + cnt[blk * NBK + j];
    __syncthreads();
    int base = blk * CHUNK;
    const int* src = ei;
    const int* dst = ei + NE;
    for (int i = threadIdx.x; i < CHUNK; i += 256) {
        int sv = src[base + i];
        int d  = dst[base + i];
        int pos = atomicAdd(&cur[d >> 7], 1);
        bval[pos] = (unsigned)sv | ((unsigned)(d & 127) << 17);
    }
}

// ---------------- P4: per-bucket counting sort -> csr, off, invdeg ---------
__global__ __launch_bounds__(256) void k_p4(const unsigned* __restrict__ bval,
                                            const int* __restrict__ bko,
                                            int* __restrict__ csr,
                                            int* __restrict__ off,
                                            float* __restrict__ invdeg) {
    __shared__ int hist[128], curk[128], sc[128];
    int b = blockIdx.x, tid = threadIdx.x;
    int s = bko[b], e = bko[b + 1];
    if (tid < 128) hist[tid] = 0;
    __syncthreads();
    for (int i = s + tid; i < e; i += 256)
        atomicAdd(&hist[bval[i] >> 17], 1);
    __syncthreads();
    if (tid < 128) sc[tid] = hist[tid];
    __syncthreads();
    for (int d = 1; d < 128; d <<= 1) {
        int x = (tid >= d && tid < 128) ? sc[tid - d] : 0;
        __syncthreads();
        if (tid < 128) sc[tid] += x;
        __syncthreads();
    }
    if (tid < 128) {
        int excl = sc[tid] - hist[tid];
        curk[tid] = excl;
        int node = b * 128 + tid;
        if (node < NN) {
            off[node] = s + excl;
            int dg = hist[tid];
            invdeg[node] = 1.0f / (float)(dg > 0 ? dg : 1);
        }
    }
    if (b == 0 && tid == 0) off[NN] = NE;
    __syncthreads();
    for (int i = s + tid; i < e; i += 256) {
        unsigned v = bval[i];
        int dl = v >> 17;
        int r = atomicAdd(&curk[dl], 1);
        csr[s + r] = (int)(v & 0x1FFFFu);
    }
}

// ---------------- one-time weight split: f32 -> (hi,lo) bf16 ----------------
__global__ void k_prepw(const float* __restrict__ W1l, const float* __restrict__ W1r,
                        const float* __restrict__ W2l, const float* __restrict__ W2r,
                        const float* __restrict__ Wc, unsigned short* __restrict__ wb) {
    int i = blockIdx.x * 256 + threadIdx.x;
    if (i < 65536) {
        int m = i >> 14, e = i & 16383;
        const float* W = (m == 0) ? W1l : (m == 1) ? W1r : (m == 2) ? W2l : W2r;
        unsigned short h, l;
        cvt_split(W[e], h, l);
        wb[m * 32768 + e] = h;
        wb[m * 32768 + 16384 + e] = l;
    } else if (i < 65536 + NC * FD) {
        int j = i - 65536;
        wb[131072 + j] = bf16_rne(Wc[j]);
    }
}

// ---------------- mean aggregation: wave/node, 4 edges x 16B per instr ----
__device__ inline void acc8(float* a, uint4 v) {
    a[0] += __uint_as_float(v.x << 16);
    a[1] += __uint_as_float(v.x & 0xFFFF0000u);
    a[2] += __uint_as_float(v.y << 16);
    a[3] += __uint_as_float(v.y & 0xFFFF0000u);
    a[4] += __uint_as_float(v.z << 16);
    a[5] += __uint_as_float(v.z & 0xFFFF0000u);
    a[6] += __uint_as_float(v.w << 16);
    a[7] += __uint_as_float(v.w & 0xFFFF0000u);
}

__global__ __launch_bounds__(256) void k_agg(const unsigned short* __restrict__ Xb,
                                             const int* __restrict__ off,
                                             const int* __restrict__ csr,
                                             const float* __restrict__ invdeg,
                                             unsigned short* __restrict__ Mb) {
    int wid = (blockIdx.x * 256 + threadIdx.x) >> 6;
    int lane = threadIdx.x & 63;
    if (wid >= NN) return;
    const int g  = lane >> 4;
    const int fc = lane & 15;
    const unsigned short* Xl = Xb + fc * 8;
    int s0 = off[wid], s1 = off[wid + 1];
    float a[8] = {};
    int e = s0;
    for (; e + 7 < s1; e += 8) {
        int r0 = csr[e + g];
        int r1 = csr[e + 4 + g];
        uint4 v0 = *reinterpret_cast<const uint4*>(Xl + ((size_t)r0 << 7));
        uint4 v1 = *reinterpret_cast<const uint4*>(Xl + ((size_t)r1 << 7));
        acc8(a, v0);
        acc8(a, v1);
    }
    for (; e < s1; e += 4) {
        int cnt = s1 - e;
        int r = csr[e + (g < cnt ? g : 0)];
        uint4 v = *reinterpret_cast<const uint4*>(Xl + ((size_t)r << 7));
        if (g < cnt) acc8(a, v);
    }
#pragma unroll
    for (int j = 0; j < 8; ++j) {
        a[j] += __shfl_xor(a[j], 32);
        a[j] += __shfl_xor(a[j], 16);
    }
    if (g == 0) {
        float w = invdeg[wid];
        uint4 o;
        o.x = (unsigned)bf16_rne(a[0] * w) | ((unsigned)bf16_rne(a[1] * w) << 16);
        o.y = (unsigned)bf16_rne(a[2] * w) | ((unsigned)bf16_rne(a[3] * w) << 16);
        o.z = (unsigned)bf16_rne(a[4] * w) | ((unsigned)bf16_rne(a[5] * w) << 16);
        o.w = (unsigned)bf16_rne(a[6] * w) | ((unsigned)bf16_rne(a[7] * w) << 16);
        *reinterpret_cast<uint4*>(Mb + (size_t)wid * FD + fc * 8) = o;
    }
}

// ---------------- dual GEMM via MFMA (+fused classifier) ----------------
template <bool FUSE>
__global__ __launch_bounds__(256, 3) void k_gemm(
        const unsigned short* __restrict__ M,
        const unsigned short* __restrict__ X,
        const unsigned short* __restrict__ Wl,
        const unsigned short* __restrict__ Wr,
        const float* __restrict__ bias,
        const unsigned short* __restrict__ Wcb,
        const float* __restrict__ bc,
        unsigned short* outb, float* outf) {
    __shared__ __align__(16) unsigned short pool[FUSE ? 21504 : 12800];
    unsigned short* Ah = pool;            // [64][40]
    unsigned short* Bh = pool + 2560;     // [128][40]
    unsigned short* Bl = pool + 7680;     // [128][40]

    const int tid = threadIdx.x;
    const int wave = tid >> 6;
    const int lane = tid & 63;
    const int wm = wave & 1;
    const int wn = wave >> 1;
    const int nb = blockIdx.x * 64;
    const int l15 = lane & 15;
    const int kb = lane >> 4;

    f32x4 acc[2][4] = {};

    for (int c = 0; c < 8; ++c) {
        const unsigned short* A = (c < 4) ? M : X;
        const unsigned short* W = (c < 4) ? Wl : Wr;
        const int kc = (c & 3) * 32;
        __syncthreads();
        {
            int row = tid >> 2, seg = tid & 3;
            int gn = nb + row;
            short8 v = {};
            if (gn < NN)
                v = *reinterpret_cast<const short8*>(A + (size_t)gn * FD + kc + seg * 8);
            *reinterpret_cast<short8*>(&Ah[row * 40 + seg * 8]) = v;
        }
#pragma unroll
        for (int r = 0; r < 2; ++r) {
            int slot = tid + 256 * r;     // < 512: 128 rows x 4 segs
            int o = slot >> 2, seg = slot & 3;
            short8 vh = *reinterpret_cast<const short8*>(W + o * FD + kc + seg * 8);
            short8 vl = *reinterpret_cast<const short8*>(W + 16384 + o * FD + kc + seg * 8);
            *reinterpret_cast<short8*>(&Bh[o * 40 + seg * 8]) = vh;
            *reinterpret_cast<short8*>(&Bl[o * 40 + seg * 8]) = vl;
        }
        __syncthreads();
        short8 a[2], b_h[4], b_l[4];
#pragma unroll
        for (int mt = 0; mt < 2; ++mt) {
            int row = wm * 32 + mt * 16 + l15;
            a[mt] = *reinterpret_cast<const short8*>(&Ah[row * 40 + kb * 8]);
        }
#pragma unroll
        for (int nt = 0; nt < 4; ++nt) {
            int o = wn * 64 + nt * 16 + l15;
            b_h[nt] = *reinterpret_cast<const short8*>(&Bh[o * 40 + kb * 8]);
            b_l[nt] = *reinterpret_cast<const short8*>(&Bl[o * 40 + kb * 8]);
        }
#pragma unroll
        for (int mt = 0; mt < 2; ++mt)
#pragma unroll
            for (int nt = 0; nt < 4; ++nt) {
                acc[mt][nt] = __builtin_amdgcn_mfma_f32_16x16x32_bf16(a[mt], b_h[nt], acc[mt][nt], 0, 0, 0);
                acc[mt][nt] = __builtin_amdgcn_mfma_f32_16x16x32_bf16(a[mt], b_l[nt], acc[mt][nt], 0, 0, 0);
            }
    }

    float bz[4];
#pragma unroll
    for (int nt = 0; nt < 4; ++nt) bz[nt] = bias[wn * 64 + nt * 16 + l15];

    if (!FUSE) {
#pragma unroll
        for (int mt = 0; mt < 2; ++mt) {
            int gn0 = nb + wm * 32 + mt * 16 + kb * 4;
#pragma unroll
            for (int r = 0; r < 4; ++r) {
                int gn = gn0 + r;
                if (gn < NN) {
#pragma unroll
                    for (int nt = 0; nt < 4; ++nt) {
                        float v = fmaxf(acc[mt][nt][r] + bz[nt], 0.f);
                        outb[(size_t)gn * FD + wn * 64 + nt * 16 + l15] = bf16_rne(v);
                    }
                }
            }
        }
    } else {
        unsigned short* Hs  = pool + 12800;   // [64][136]
        unsigned short* Wcs = pool;           // [40][136] (reuses staging)
        __syncthreads();
#pragma unroll
        for (int r = 0; r < 3; ++r) {
            int slot = tid + 256 * r;         // 640 slots: 40 rows x 16 segs
            if (slot < 640) {
                int row = slot >> 4, seg = slot & 15;
                *reinterpret_cast<short8*>(&Wcs[row * 136 + seg * 8]) =
                    *reinterpret_cast<const short8*>(Wcb + row * FD + seg * 8);
            }
        }
#pragma unroll
        for (int mt = 0; mt < 2; ++mt) {
            int row0 = wm * 32 + mt * 16 + kb * 4;
#pragma unroll
            for (int r = 0; r < 4; ++r) {
#pragma unroll
                for (int nt = 0; nt < 4; ++nt) {
                    float v = fmaxf(acc[mt][nt][r] + bz[nt], 0.f);
                    Hs[(row0 + r) * 136 + wn * 64 + nt * 16 + l15] = bf16_rne(v);
                }
            }
        }
        __syncthreads();
        f32x4 c2[3] = {};
#pragma unroll
        for (int kk = 0; kk < 4; ++kk) {
            short8 af = *reinterpret_cast<const short8*>(
                &Hs[(wave * 16 + l15) * 136 + kk * 32 + kb * 8]);
#pragma unroll
            for (int t = 0; t < 3; ++t) {
                short8 bf = *reinterpret_cast<const short8*>(
                    &Wcs[(t * 16 + l15) * 136 + kk * 32 + kb * 8]);
                c2[t] = __builtin_amdgcn_mfma_f32_16x16x32_bf16(af, bf, c2[t], 0, 0, 0);
            }
        }
#pragma unroll
        for (int t = 0; t < 3; ++t) {
            int cls = t * 16 + l15;
            if (cls < NC) {
#pragma unroll
                for (int r = 0; r < 4; ++r) {
                    int gn = nb + wave * 16 + kb * 4 + r;
                    if (gn < NN)
                        outf[(size_t)gn * NC + cls] = c2[t][r] + bc[cls];
                }
            }
        }
    }
}

extern "C" void kernel_launch(void* const* d_in, const int* in_sizes, int n_in,
                              void* d_out, int out_size, void* d_ws, size_t ws_size,
                              hipStream_t stream) {
    const float* x   = (const float*)d_in[0];
    const int*   ei  = (const int*)d_in[1];
    const float* W1l = (const float*)d_in[3];
    const float* b1l = (const float*)d_in[4];
    const float* W1r = (const float*)d_in[5];
    const float* W2l = (const float*)d_in[6];
    const float* b2l = (const float*)d_in[7];
    const float* W2r = (const float*)d_in[8];
    const float* Wc  = (const float*)d_in[9];
    const float* bc  = (const float*)d_in[10];
    float* out = (float*)d_out;

    char* ws = (char*)d_ws;
    int*   off    = (int*)(ws + WS_OFF);
    float* invdeg = (float*)(ws + WS_INVDEG);
    int*   cnt    = (int*)(ws + WS_CNT);
    int*   btot   = (int*)(ws + WS_BTOT);
    int*   bko    = (int*)(ws + WS_BKO);
    unsigned short* wb = (unsigned short*)(ws + WS_WB);
    int*   csr    = (int*)(ws + WS_CSR);
    unsigned short* xb = (unsigned short*)(ws + WS_XB);
    unsigned short* mb = (unsigned short*)(ws + WS_MB);
    unsigned short* hb = (unsigned short*)(ws + WS_HB);
    unsigned* bval = (unsigned*)(ws + WS_HB);  // consumed by k_p4 before hb written

    k_prepw<<<276, 256, 0, stream>>>(W1l, W1r, W2l, W2r, Wc, wb);
    k_p1<<<CONVB + HISTB, 256, 0, stream>>>(ei, cnt, x, xb);
    k_p2a<<<NBK, 256, 0, stream>>>(cnt, btot);
    k_p2b<<<1, 256, 0, stream>>>(btot, bko);
    k_p3<<<HISTB, 256, 0, stream>>>(ei, cnt, bko, bval);
    k_p4<<<NBK, 256, 0, stream>>>(bval, bko, csr, off, invdeg);

    const int GG = (NN + 63) / 64;   // 1563

    // layer 1
    k_agg<<<(NN + 3) / 4, 256, 0, stream>>>(xb, off, csr, invdeg, mb);
    k_gemm<false><<<GG, 256, 0, stream>>>(mb, xb, wb, wb + 32768, b1l,
                                          nullptr, nullptr, hb, nullptr);
    // layer 2 + fused classifier
    k_agg<<<(NN + 3) / 4, 256, 0, stream>>>(hb, off, csr, invdeg, mb);
    k_gemm<true><<<GG, 256, 0, stream>>>(mb, hb, wb + 65536, wb + 98304, b2l,
                                         wb + 131072, bc, nullptr, out);
}